// Round 4
// baseline (554.243 us; speedup 1.0000x reference)
//
#include <hip/hip_runtime.h>
#include <hip/hip_bf16.h>
#include <math.h>

// T5 encoder block: B=2, S=1024, D_MODEL=1024, H=16, D_KV=64, D_FF=4096
// NUM_BUCKETS=32, MAX_DIST=128, EPS=1e-6.
// ROUND 4: runtime input-dtype detection (fp32 vs bf16 device buffers).
// Core pipeline is bf16 MFMA; only the edges (input reads, final store)
// branch on the detected mode.  mode: 1 = fp32 buffers, 0 = bf16 buffers.

typedef __bf16 bf16_t;
typedef __attribute__((ext_vector_type(8))) __bf16 bf16x8;
typedef __attribute__((ext_vector_type(4))) __bf16 bf16x4;
typedef __attribute__((ext_vector_type(4))) float floatx4;

// ---------------------------------------------------------------------------
// Detect input dtype from hidden_states bit patterns.
// bf16 data: every low half-word of a u32 is a genuine ~N(0,1) bf16 ->
//   exponent field in [97,140] (|v| in [2^-30, 2^13]) essentially always.
// fp32 data: low half-word exponent field = random mantissa bits -> uniform;
//   P(all 256 in band) ~ 1e-197.
// ---------------------------------------------------------------------------
__global__ void detect_mode_kernel(const unsigned int* __restrict__ bits,
                                   int* __restrict__ mode) {
  int t = threadIdx.x;
  unsigned int w = bits[t];
  unsigned int e = (w >> 7) & 0xffu;  // exponent field of low half as bf16
  int p = (e >= 97u && e <= 140u) ? 1 : 0;
  __shared__ int cnt;
  if (t == 0) cnt = 0;
  __syncthreads();
  atomicAdd(&cnt, p);
  __syncthreads();
  if (t == 0) *mode = (cnt == 256) ? 0 : 1;  // 0=bf16 inputs, 1=fp32 inputs
}

// ---------------------------------------------------------------------------
// Canonicalize small params (ln1_w, ln2_w, rel_bias) to bf16 in ws.
// ---------------------------------------------------------------------------
__global__ void convert_small_kernel(const void* __restrict__ ln1,
                                     const void* __restrict__ ln2,
                                     const void* __restrict__ rb,
                                     bf16_t* __restrict__ ln1c,
                                     bf16_t* __restrict__ ln2c,
                                     bf16_t* __restrict__ relc,
                                     const int* __restrict__ modep) {
  const int f32 = *modep;
  for (int idx = threadIdx.x; idx < 2560; idx += 256) {
    const void* src;
    bf16_t* dst;
    int j;
    if (idx < 1024) { src = ln1; dst = ln1c; j = idx; }
    else if (idx < 2048) { src = ln2; dst = ln2c; j = idx - 1024; }
    else { src = rb; dst = relc; j = idx - 2048; }
    if (f32) dst[j] = (bf16_t)((const float*)src)[j];
    else dst[j] = ((const bf16_t*)src)[j];
  }
}

// ---------------------------------------------------------------------------
// Relative-position bias table: table[h][dpos] = rel_bias[bucket(k-q)][h]
// ---------------------------------------------------------------------------
__global__ void bias_table_kernel(const bf16_t* __restrict__ rel_bias,
                                  float* __restrict__ table) {
  int idx = blockIdx.x * 256 + threadIdx.x;  // h*2048 + dpos
  int h = idx >> 11;
  int dpos = idx & 2047;
  int delta = dpos - 1023;  // k - q
  if (delta > 1023) delta = 1023;
  int side = (delta > 0) ? 16 : 0;  // num_buckets//2 = 16
  int rp = (delta < 0) ? -delta : delta;
  int bucket;
  if (rp < 8) {  // max_exact = 8
    bucket = side + rp;
  } else {
    float t1 = logf((float)rp * 0.125f);
    float t2 = t1 / 2.7725887f;  // float32(log(16))
    float t3 = t2 * 8.0f;
    int v = 8 + (int)t3;
    if (v > 15) v = 15;
    bucket = side + v;
  }
  table[idx] = (float)rel_bias[bucket * 16 + h];
}

// ---------------------------------------------------------------------------
// T5 RMSNorm, one block per row (D=1024).  X dtype: bf16 ws buffer, or the
// harness input (branch on mode when x_is_input).  w is canonical bf16.
// ---------------------------------------------------------------------------
__global__ __launch_bounds__(256) void rmsnorm_kernel(
    const void* __restrict__ X, const bf16_t* __restrict__ w,
    bf16_t* __restrict__ Y, const int* __restrict__ modep, int x_is_input) {
  const int D = 1024;
  const int f32 = x_is_input && *modep;
  int row = blockIdx.x;
  int t = threadIdx.x;
  bf16_t* y = Y + (size_t)row * D;

  float f[4];
  if (f32) {
    float4 v = ((const float4*)((const float*)X + (size_t)row * D))[t];
    f[0] = v.x; f[1] = v.y; f[2] = v.z; f[3] = v.w;
  } else {
    bf16x4 v = ((const bf16x4*)((const bf16_t*)X + (size_t)row * D))[t];
#pragma unroll
    for (int j = 0; j < 4; ++j) f[j] = (float)v[j];
  }
  float s = 0.f;
#pragma unroll
  for (int j = 0; j < 4; ++j) s += f[j] * f[j];
#pragma unroll
  for (int off = 32; off > 0; off >>= 1) s += __shfl_down(s, off);
  __shared__ float red[4];
  int lane = t & 63, wave = t >> 6;
  if (lane == 0) red[wave] = s;
  __syncthreads();
  float tot = red[0] + red[1] + red[2] + red[3];
  float scale = rsqrtf(tot * (1.0f / D) + 1e-6f);
  bf16x4 wv4 = *(const bf16x4*)(w + t * 4);
  bf16x4 o;
#pragma unroll
  for (int j = 0; j < 4; ++j) o[j] = (bf16_t)(f[j] * scale * (float)wv4[j]);
  *(bf16x4*)(y + t * 4) = o;
}

// ---------------------------------------------------------------------------
// GEMM: C[M,N] = epilogue(A[M,K] @ W[N,K]^T).  op: 0 store, 1 +R, 2 relu.
// A is always bf16 (ws buffer).  W is harness input (dtype per mode).
// R: r_is_input -> harness dtype, else bf16 ws.  C: c_is_output -> harness
// dtype, else bf16 ws.  128x128 tile, BK=32, m92-style staging.
// ---------------------------------------------------------------------------
#define BM 128
#define BN 128
#define BK 32

__global__ __launch_bounds__(256, 2) void gemm_bt_kernel(
    const bf16_t* __restrict__ A, const void* __restrict__ W,
    const void* __restrict__ R, void* __restrict__ C,
    int M, int N, int K, int op, const int* __restrict__ modep,
    int r_is_input, int c_is_output) {
  __shared__ bf16_t As[BM * BK];  // [row][32]
  __shared__ bf16_t Bs[BN * BK];  // [n][32]

  const int mode = *modep;  // 1 = fp32 harness buffers
  const int tid = threadIdx.x;
  const int lane = tid & 63;
  const int wv = tid >> 6;
  const int wm = wv & 1;
  const int wn = wv >> 1;
  const int lr = lane & 15;
  const int lq = lane >> 4;

  const size_t row0 = (size_t)blockIdx.x * BM;
  const size_t col0 = (size_t)blockIdx.y * BN;

  const bf16_t* Abase = A + row0 * K;

  floatx4 acc[4][4] = {};

  for (int kt = 0; kt < K; kt += BK) {
    // A: 128 rows x 32 cols = 512 chunks of 8 bf16; 2 per thread
#pragma unroll
    for (int i = 0; i < 2; ++i) {
      int chunk = i * 256 + tid;
      int r = chunk >> 2;
      int kc = (chunk & 3) << 3;
      *(bf16x8*)(As + chunk * 8) =
          *(const bf16x8*)(Abase + (size_t)r * K + kt + kc);
    }
    // W: same mapping, dtype-aware
    if (mode) {
      const float* Wf = (const float*)W;
#pragma unroll
      for (int i = 0; i < 2; ++i) {
        int chunk = i * 256 + tid;
        int r = chunk >> 2;
        int kc = (chunk & 3) << 3;
        const float* p = Wf + (col0 + (size_t)r) * K + kt + kc;
        float4 f0 = *(const float4*)p;
        float4 f1v = *(const float4*)(p + 4);
        bf16x8 o;
        o[0] = (bf16_t)f0.x; o[1] = (bf16_t)f0.y;
        o[2] = (bf16_t)f0.z; o[3] = (bf16_t)f0.w;
        o[4] = (bf16_t)f1v.x; o[5] = (bf16_t)f1v.y;
        o[6] = (bf16_t)f1v.z; o[7] = (bf16_t)f1v.w;
        *(bf16x8*)(Bs + chunk * 8) = o;
      }
    } else {
      const bf16_t* Wb = (const bf16_t*)W;
#pragma unroll
      for (int i = 0; i < 2; ++i) {
        int chunk = i * 256 + tid;
        int r = chunk >> 2;
        int kc = (chunk & 3) << 3;
        *(bf16x8*)(Bs + chunk * 8) =
            *(const bf16x8*)(Wb + (col0 + (size_t)r) * K + kt + kc);
      }
    }
    __syncthreads();

    bf16x8 af[4], bfr[4];
#pragma unroll
    for (int mi = 0; mi < 4; ++mi)
      af[mi] = *(const bf16x8*)(As + (wm * 64 + mi * 16 + lr) * BK + lq * 8);
#pragma unroll
    for (int nj = 0; nj < 4; ++nj)
      bfr[nj] = *(const bf16x8*)(Bs + (wn * 64 + nj * 16 + lr) * BK + lq * 8);

#pragma unroll
    for (int mi = 0; mi < 4; ++mi)
#pragma unroll
      for (int nj = 0; nj < 4; ++nj)
        acc[mi][nj] = __builtin_amdgcn_mfma_f32_16x16x32_bf16(
            af[mi], bfr[nj], acc[mi][nj], 0, 0, 0);
    __syncthreads();
  }

  const int r_f32 = r_is_input && mode;
  const int c_f32 = c_is_output && mode;
#pragma unroll
  for (int mi = 0; mi < 4; ++mi) {
#pragma unroll
    for (int nj = 0; nj < 4; ++nj) {
      size_t r = row0 + wm * 64 + mi * 16 + lq * 4;
      size_t c = col0 + wn * 64 + nj * 16 + lr;
#pragma unroll
      for (int t = 0; t < 4; ++t) {
        float v = acc[mi][nj][t];
        size_t idx = (r + t) * N + c;
        if (op == 1) {
          float rv = r_f32 ? ((const float*)R)[idx]
                           : (float)((const bf16_t*)R)[idx];
          v += rv;
        } else if (op == 2) {
          v = v > 0.f ? v : 0.f;
        }
        if (c_f32) ((float*)C)[idx] = v;
        else ((bf16_t*)C)[idx] = (bf16_t)v;
      }
    }
  }
}

// ---------------------------------------------------------------------------
// Flash attention, T5 style (+rel-pos bias, no 1/sqrt(d)).  D_KV=64.
// All operands are ws bf16.  Grid (S/64, H, B); 4 waves; wave owns 16 q rows.
// ---------------------------------------------------------------------------
__global__ __launch_bounds__(256) void attn_kernel(
    const bf16_t* __restrict__ Q, const bf16_t* __restrict__ K,
    const bf16_t* __restrict__ V, const float* __restrict__ bias_table,
    bf16_t* __restrict__ O) {
  const int S = 1024, H = 16;
  const int qt = blockIdx.x;
  const int h = blockIdx.y;
  const int b = blockIdx.z;
  const int tid = threadIdx.x;
  const int lane = tid & 63;
  const int wv = tid >> 6;
  const int lr = lane & 15;
  const int lq = lane >> 4;

  __shared__ bf16_t Ks[64 * 64];     // [key][d]
  __shared__ bf16_t Vt[64 * 64];     // [d][key]
  __shared__ bf16_t Ps[4][16 * 64];  // per-wave P tile [q][key]

  const size_t headoff = ((size_t)b * S * H + h) * 64;
  const size_t rstride = (size_t)H * 64;  // 1024

  const int q0 = qt * 64 + wv * 16;

  bf16x8 qf[2];
#pragma unroll
  for (int c = 0; c < 2; ++c)
    qf[c] = *(const bf16x8*)(Q + headoff + (size_t)(q0 + lr) * rstride + c * 32 + lq * 8);

  float m_i[4], l_i[4];
  floatx4 o_acc[4];
#pragma unroll
  for (int i = 0; i < 4; ++i) {
    m_i[i] = -1e30f;
    l_i[i] = 0.f;
    o_acc[i] = (floatx4){0.f, 0.f, 0.f, 0.f};
  }

  const float* btab = bias_table + h * 2048;

  for (int kt = 0; kt < 16; ++kt) {
    const int k0 = kt * 64;
#pragma unroll
    for (int i = 0; i < 2; ++i) {
      int chunk = i * 256 + tid;
      int kr = chunk >> 3;
      int dc = (chunk & 7) * 8;
      *(bf16x8*)(Ks + kr * 64 + dc) =
          *(const bf16x8*)(K + headoff + (size_t)(k0 + kr) * rstride + dc);
      bf16x8 vvv = *(const bf16x8*)(V + headoff + (size_t)(k0 + kr) * rstride + dc);
#pragma unroll
      for (int j = 0; j < 8; ++j) Vt[(dc + j) * 64 + kr] = vvv[j];
    }
    __syncthreads();

    // S = Q K^T
    floatx4 s_acc[4];
#pragma unroll
    for (int g = 0; g < 4; ++g) {
      floatx4 a = (floatx4){0.f, 0.f, 0.f, 0.f};
#pragma unroll
      for (int c = 0; c < 2; ++c) {
        bf16x8 kf = *(const bf16x8*)(Ks + (g * 16 + lr) * 64 + c * 32 + lq * 8);
        a = __builtin_amdgcn_mfma_f32_16x16x32_bf16(qf[c], kf, a, 0, 0, 0);
      }
      s_acc[g] = a;
    }

    // + bias, row max.  lane holds S[q=q0+lq*4+t][key=k0+g*16+lr]
    float rowmax[4] = {-1e30f, -1e30f, -1e30f, -1e30f};
#pragma unroll
    for (int g = 0; g < 4; ++g) {
#pragma unroll
      for (int t = 0; t < 4; ++t) {
        int qg = q0 + lq * 4 + t;
        int kg = k0 + g * 16 + lr;
        float sv = s_acc[g][t] + btab[kg - qg + 1023];
        s_acc[g][t] = sv;
        rowmax[t] = fmaxf(rowmax[t], sv);
      }
    }
#pragma unroll
    for (int off = 1; off < 16; off <<= 1)
#pragma unroll
      for (int t = 0; t < 4; ++t)
        rowmax[t] = fmaxf(rowmax[t], __shfl_xor(rowmax[t], off));

    float alpha[4], rowsum[4];
#pragma unroll
    for (int t = 0; t < 4; ++t) {
      float mnew = fmaxf(m_i[t], rowmax[t]);
      alpha[t] = __expf(m_i[t] - mnew);
      m_i[t] = mnew;
      rowsum[t] = 0.f;
    }
#pragma unroll
    for (int g = 0; g < 4; ++g) {
#pragma unroll
      for (int t = 0; t < 4; ++t) {
        float p = __expf(s_acc[g][t] - m_i[t]);
        rowsum[t] += p;
        Ps[wv][(lq * 4 + t) * 64 + g * 16 + lr] = (bf16_t)p;
      }
    }
#pragma unroll
    for (int off = 1; off < 16; off <<= 1)
#pragma unroll
      for (int t = 0; t < 4; ++t) rowsum[t] += __shfl_xor(rowsum[t], off);
#pragma unroll
    for (int t = 0; t < 4; ++t) l_i[t] = l_i[t] * alpha[t] + rowsum[t];
#pragma unroll
    for (int g = 0; g < 4; ++g)
#pragma unroll
      for (int t = 0; t < 4; ++t) o_acc[g][t] *= alpha[t];

    __syncthreads();  // P writes visible

    bf16x8 pf[2];
#pragma unroll
    for (int c = 0; c < 2; ++c)
      pf[c] = *(const bf16x8*)(&Ps[wv][lr * 64 + c * 32 + lq * 8]);

    // O += P @ V
#pragma unroll
    for (int g = 0; g < 4; ++g) {
#pragma unroll
      for (int c = 0; c < 2; ++c) {
        bf16x8 vf = *(const bf16x8*)(Vt + (g * 16 + lr) * 64 + c * 32 + lq * 8);
        o_acc[g] = __builtin_amdgcn_mfma_f32_16x16x32_bf16(pf[c], vf, o_acc[g], 0, 0, 0);
      }
    }
    __syncthreads();
  }

  float inv_l[4];
#pragma unroll
  for (int t = 0; t < 4; ++t) inv_l[t] = 1.f / l_i[t];
#pragma unroll
  for (int g = 0; g < 4; ++g) {
#pragma unroll
    for (int t = 0; t < 4; ++t) {
      int qg = q0 + lq * 4 + t;
      int d = g * 16 + lr;
      O[headoff + (size_t)qg * rstride + d] = (bf16_t)(o_acc[g][t] * inv_l[t]);
    }
  }
}

// ---------------------------------------------------------------------------
extern "C" void kernel_launch(void* const* d_in, const int* in_sizes, int n_in,
                              void* d_out, int out_size, void* d_ws,
                              size_t ws_size, hipStream_t stream) {
  const void* hs = d_in[0];
  const void* ln1_w = d_in[1];
  const void* wq = d_in[2];
  const void* wk = d_in[3];
  const void* wvv = d_in[4];
  const void* wo = d_in[5];
  const void* rel_bias = d_in[6];
  const void* ln2_w = d_in[7];
  const void* wi = d_in[8];
  const void* wo_ff = d_in[9];

  const int M = 2048, D = 1024, FF = 4096;

  // ws: mode(16B) | btab 128KB | ln1c 2KB | ln2c 2KB | relc 1KB+pad |
  //     bufA..D 4MB x4 | f1 16MB   ~= 33.7 MB (round-3 guard proved ws fits)
  char* w = (char*)d_ws;
  int* modep = (int*)w;      w += 16;
  float* btab = (float*)w;   w += 16 * 2048 * 4;
  bf16_t* ln1c = (bf16_t*)w; w += 1024 * 2;
  bf16_t* ln2c = (bf16_t*)w; w += 1024 * 2;
  bf16_t* relc = (bf16_t*)w; w += 512 * 2 + 1024;  // pad to 16B multiples
  bf16_t* bufA = (bf16_t*)w; w += (size_t)M * D * 2;  // x, then ctx
  bf16_t* bufB = (bf16_t*)w; w += (size_t)M * D * 2;  // q, then hbuf
  bf16_t* bufC = (bf16_t*)w; w += (size_t)M * D * 2;  // k, then y
  bf16_t* bufD = (bf16_t*)w; w += (size_t)M * D * 2;  // v
  bf16_t* f1 = (bf16_t*)w;   w += (size_t)M * FF * 2;
  if ((size_t)(w - (char*)d_ws) > ws_size) return;

  bf16_t* x = bufA;
  bf16_t* q = bufB;
  bf16_t* k = bufC;
  bf16_t* v = bufD;

  detect_mode_kernel<<<1, 256, 0, stream>>>((const unsigned int*)hs, modep);
  convert_small_kernel<<<1, 256, 0, stream>>>(ln1_w, ln2_w, rel_bias,
                                              ln1c, ln2c, relc, modep);
  bias_table_kernel<<<128, 256, 0, stream>>>(relc, btab);
  rmsnorm_kernel<<<M, 256, 0, stream>>>(hs, ln1c, x, modep, 1);

  dim3 g1(M / BM, D / BN);  // (16, 8)
  gemm_bt_kernel<<<g1, 256, 0, stream>>>(x, wq, nullptr, q, M, D, D, 0, modep, 0, 0);
  gemm_bt_kernel<<<g1, 256, 0, stream>>>(x, wk, nullptr, k, M, D, D, 0, modep, 0, 0);
  gemm_bt_kernel<<<g1, 256, 0, stream>>>(x, wvv, nullptr, v, M, D, D, 0, modep, 0, 0);

  bf16_t* ctx = bufA;  // x dead
  dim3 ga(16, 16, 2);
  attn_kernel<<<ga, 256, 0, stream>>>(q, k, v, btab, ctx);

  bf16_t* hbuf = bufB;  // q dead
  gemm_bt_kernel<<<g1, 256, 0, stream>>>(ctx, wo, hs, hbuf, M, D, D, 1, modep, 1, 0);

  bf16_t* y = bufC;  // k dead
  rmsnorm_kernel<<<M, 256, 0, stream>>>(hbuf, ln2c, y, modep, 0);

  dim3 g2(M / BM, FF / BN);  // (16, 32)
  gemm_bt_kernel<<<g2, 256, 0, stream>>>(y, wi, nullptr, f1, M, FF, D, 2, modep, 0, 0);
  gemm_bt_kernel<<<g1, 256, 0, stream>>>(f1, wo_ff, hbuf, d_out, M, D, FF, 1, modep, 0, 1);
}

// Round 5
// 313.075 us; speedup vs baseline: 1.7703x; 1.7703x over previous
//
#include <hip/hip_runtime.h>
#include <hip/hip_bf16.h>
#include <math.h>

// T5 encoder block on MI355X. B=2, S=1024, D_MODEL=1024, H=16, D_KV=64,
// D_FF=4096, NUM_BUCKETS=32, MAX_DIST=128, EPS=1e-6.
// Harness buffers are fp32 (established round 4; fp32 out passed).
// Internal pipeline: bf16 MFMA, fp32 accumulate.
// ROUND 5: occupancy attack — fused QKV (384 blocks), split-K for the two
// N=1024 GEMMs (WO x2, WO_FF x4), DMA (global_load_lds) A-staging restored.

typedef __bf16 bf16_t;
typedef __attribute__((ext_vector_type(8))) __bf16 bf16x8;
typedef __attribute__((ext_vector_type(4))) __bf16 bf16x4;
typedef __attribute__((ext_vector_type(4))) float floatx4;

#define GLOBAL_AS(p) ((const __attribute__((address_space(1))) void*)(p))
#define LDS_AS(p)    ((__attribute__((address_space(3))) void*)(p))

// ---------------------------------------------------------------------------
// Relative-position bias table: table[h][dpos] = rel_bias[bucket(k-q)][h]
// rel_bias is fp32 [32,16].
// ---------------------------------------------------------------------------
__global__ void bias_table_kernel(const float* __restrict__ rel_bias,
                                  float* __restrict__ table) {
  int idx = blockIdx.x * 256 + threadIdx.x;  // h*2048 + dpos
  int h = idx >> 11;
  int dpos = idx & 2047;
  int delta = dpos - 1023;  // k - q
  if (delta > 1023) delta = 1023;
  int side = (delta > 0) ? 16 : 0;  // num_buckets//2 = 16
  int rp = (delta < 0) ? -delta : delta;
  int bucket;
  if (rp < 8) {  // max_exact = 8
    bucket = side + rp;
  } else {
    float t1 = logf((float)rp * 0.125f);
    float t2 = t1 / 2.7725887f;  // float32(log(16))
    float t3 = t2 * 8.0f;
    int v = 8 + (int)t3;
    if (v > 15) v = 15;
    bucket = side + v;
  }
  table[idx] = rel_bias[bucket * 16 + h];
}

// ---------------------------------------------------------------------------
// T5 RMSNorm, one block per row (D=1024). w is fp32 (harness).
// x_f32: input is fp32 (harness hs) vs bf16 (ws buffer). Output bf16.
// ---------------------------------------------------------------------------
__global__ __launch_bounds__(256) void rmsnorm_kernel(
    const void* __restrict__ X, const float* __restrict__ w,
    bf16_t* __restrict__ Y, int x_f32) {
  const int D = 1024;
  int row = blockIdx.x;
  int t = threadIdx.x;
  bf16_t* y = Y + (size_t)row * D;

  float f[4];
  if (x_f32) {
    float4 v = ((const float4*)((const float*)X + (size_t)row * D))[t];
    f[0] = v.x; f[1] = v.y; f[2] = v.z; f[3] = v.w;
  } else {
    bf16x4 v = ((const bf16x4*)((const bf16_t*)X + (size_t)row * D))[t];
#pragma unroll
    for (int j = 0; j < 4; ++j) f[j] = (float)v[j];
  }
  float s = 0.f;
#pragma unroll
  for (int j = 0; j < 4; ++j) s += f[j] * f[j];
#pragma unroll
  for (int off = 32; off > 0; off >>= 1) s += __shfl_down(s, off);
  __shared__ float red[4];
  int lane = t & 63, wave = t >> 6;
  if (lane == 0) red[wave] = s;
  __syncthreads();
  float tot = red[0] + red[1] + red[2] + red[3];
  float scale = rsqrtf(tot * (1.0f / D) + 1e-6f);
  float4 wv4 = ((const float4*)w)[t];
  bf16x4 o;
  o[0] = (bf16_t)(f[0] * scale * wv4.x);
  o[1] = (bf16_t)(f[1] * scale * wv4.y);
  o[2] = (bf16_t)(f[2] * scale * wv4.z);
  o[3] = (bf16_t)(f[3] * scale * wv4.w);
  *(bf16x4*)(y + t * 4) = o;
}

// ---------------------------------------------------------------------------
// GEMM: C[M,N](+slice) = epilogue(A[M,K] @ Wsel[N,K]^T over K-slice).
// A: bf16 ws. W0/W1/W2: fp32 weights, selected by output-column block
// (wsel_cols per pointer; pass same pointer 3x + huge wsel_cols to disable).
// Split-K: blockIdx.z picks K-slice [z*klen, (z+1)*klen) and output slice
// C + z*M*N.  op: 0 = store, 2 = relu-store.  Output bf16.
// 128x128 tile, BK=32; A staged via global_load_lds (16B), W converted
// fp32->bf16 through VGPRs.
// ---------------------------------------------------------------------------
#define BM 128
#define BN 128
#define BK 32

__global__ __launch_bounds__(256, 2) void gemm_bt_kernel(
    const bf16_t* __restrict__ A, const float* __restrict__ W0,
    const float* __restrict__ W1, const float* __restrict__ W2,
    bf16_t* __restrict__ C, int M, int K_total, int klen, int N,
    int wsel_cols, int op) {
  __shared__ bf16_t As[BM * BK];  // [row][32]
  __shared__ bf16_t Bs[BN * BK];  // [n][32]

  const int tid = threadIdx.x;
  const int lane = tid & 63;
  const int wv = tid >> 6;
  const int wm = wv & 1;
  const int wn = wv >> 1;
  const int lr = lane & 15;
  const int lq = lane >> 4;

  const size_t row0 = (size_t)blockIdx.x * BM;
  const size_t col0 = (size_t)blockIdx.y * BN;
  const int k0 = blockIdx.z * klen;

  // W pointer select (QKV fusion): col0 / wsel_cols -> W0/W1/W2
  const float* Ws = W0;
  size_t wc0 = col0;
  if ((int)col0 >= wsel_cols) {
    if ((int)col0 < 2 * wsel_cols) { Ws = W1; wc0 = col0 - wsel_cols; }
    else { Ws = W2; wc0 = col0 - 2 * (size_t)wsel_cols; }
  }

  const bf16_t* Abase = A + row0 * K_total;
  const float* Wbase = Ws + wc0 * K_total;
  bf16_t* Cs = C + (size_t)blockIdx.z * M * N;

  floatx4 acc[4][4] = {};

  for (int kt = k0; kt < k0 + klen; kt += BK) {
    // A: 128x32 bf16 = 512 16B-chunks, 2 per thread, via DMA
#pragma unroll
    for (int i = 0; i < 2; ++i) {
      int chunk = i * 256 + tid;
      int r = chunk >> 2;
      int kc = (chunk & 3) << 3;
      __builtin_amdgcn_global_load_lds(
          GLOBAL_AS(Abase + (size_t)r * K_total + kt + kc),
          LDS_AS(As + (size_t)(i * 256 + wv * 64) * 8), 16, 0, 0);
    }
    // W: fp32 -> bf16 through VGPRs, same LDS mapping
#pragma unroll
    for (int i = 0; i < 2; ++i) {
      int chunk = i * 256 + tid;
      int r = chunk >> 2;
      int kc = (chunk & 3) << 3;
      const float* p = Wbase + (size_t)r * K_total + kt + kc;
      float4 f0 = *(const float4*)p;
      float4 f1v = *(const float4*)(p + 4);
      bf16x8 o;
      o[0] = (bf16_t)f0.x; o[1] = (bf16_t)f0.y;
      o[2] = (bf16_t)f0.z; o[3] = (bf16_t)f0.w;
      o[4] = (bf16_t)f1v.x; o[5] = (bf16_t)f1v.y;
      o[6] = (bf16_t)f1v.z; o[7] = (bf16_t)f1v.w;
      *(bf16x8*)(Bs + chunk * 8) = o;
    }
    __syncthreads();

    bf16x8 af[4], bfr[4];
#pragma unroll
    for (int mi = 0; mi < 4; ++mi)
      af[mi] = *(const bf16x8*)(As + (wm * 64 + mi * 16 + lr) * BK + lq * 8);
#pragma unroll
    for (int nj = 0; nj < 4; ++nj)
      bfr[nj] = *(const bf16x8*)(Bs + (wn * 64 + nj * 16 + lr) * BK + lq * 8);

#pragma unroll
    for (int mi = 0; mi < 4; ++mi)
#pragma unroll
      for (int nj = 0; nj < 4; ++nj)
        acc[mi][nj] = __builtin_amdgcn_mfma_f32_16x16x32_bf16(
            af[mi], bfr[nj], acc[mi][nj], 0, 0, 0);
    __syncthreads();
  }

#pragma unroll
  for (int mi = 0; mi < 4; ++mi) {
#pragma unroll
    for (int nj = 0; nj < 4; ++nj) {
      size_t r = row0 + wm * 64 + mi * 16 + lq * 4;
      size_t c = col0 + wn * 64 + nj * 16 + lr;
#pragma unroll
      for (int t = 0; t < 4; ++t) {
        float v = acc[mi][nj][t];
        if (op == 2) v = v > 0.f ? v : 0.f;
        Cs[(r + t) * N + c] = (bf16_t)v;
      }
    }
  }
}

// ---------------------------------------------------------------------------
// Split-K reduce + residual.  out = residual + sum_s part[s], 8 elems/thread.
// residual: res_f32 (fp32) if non-null else res_b16 (bf16).
// output: out_f32 (fp32) if non-null else out_b16 (bf16).
// n = 2048*1024 elems; grid 1024 x 256.
// ---------------------------------------------------------------------------
__global__ __launch_bounds__(256) void reduce_kernel(
    const bf16_t* __restrict__ part, int splits,
    const float* __restrict__ res_f32, const bf16_t* __restrict__ res_b16,
    float* __restrict__ out_f32, bf16_t* __restrict__ out_b16) {
  const size_t SLICE = (size_t)2048 * 1024;
  size_t i = ((size_t)blockIdx.x * 256 + threadIdx.x) * 8;

  float s[8] = {0.f, 0.f, 0.f, 0.f, 0.f, 0.f, 0.f, 0.f};
  for (int sp = 0; sp < splits; ++sp) {
    bf16x8 p = *(const bf16x8*)(part + sp * SLICE + i);
#pragma unroll
    for (int j = 0; j < 8; ++j) s[j] += (float)p[j];
  }
  if (res_f32) {
    float4 a = *(const float4*)(res_f32 + i);
    float4 b = *(const float4*)(res_f32 + i + 4);
    s[0] += a.x; s[1] += a.y; s[2] += a.z; s[3] += a.w;
    s[4] += b.x; s[5] += b.y; s[6] += b.z; s[7] += b.w;
  } else {
    bf16x8 r = *(const bf16x8*)(res_b16 + i);
#pragma unroll
    for (int j = 0; j < 8; ++j) s[j] += (float)r[j];
  }
  if (out_f32) {
    float4 a, b;
    a.x = s[0]; a.y = s[1]; a.z = s[2]; a.w = s[3];
    b.x = s[4]; b.y = s[5]; b.z = s[6]; b.w = s[7];
    *(float4*)(out_f32 + i) = a;
    *(float4*)(out_f32 + i + 4) = b;
  } else {
    bf16x8 o;
#pragma unroll
    for (int j = 0; j < 8; ++j) o[j] = (bf16_t)s[j];
    *(bf16x8*)(out_b16 + i) = o;
  }
}

// ---------------------------------------------------------------------------
// Flash attention, T5 style (+rel-pos bias, no 1/sqrt(d)).  D_KV=64.
// QKV packed [2048, 3072]: Q cols [0,1024), K [1024,2048), V [2048,3072),
// head h at +h*64.  O = ctx [2048,1024].
// Grid (S/64, H, B); 4 waves; wave owns 16 q rows.
// ---------------------------------------------------------------------------
__global__ __launch_bounds__(256) void attn_kernel(
    const bf16_t* __restrict__ QKV, const float* __restrict__ bias_table,
    bf16_t* __restrict__ O) {
  const int S = 1024, H = 16;
  const int QS = 3072;   // qkv row stride
  const int OS = 1024;   // ctx row stride
  const int qt = blockIdx.x;
  const int h = blockIdx.y;
  const int b = blockIdx.z;
  const int tid = threadIdx.x;
  const int lane = tid & 63;
  const int wv = tid >> 6;
  const int lr = lane & 15;
  const int lq = lane >> 4;

  __shared__ bf16_t Ks[64 * 64];     // [key][d]
  __shared__ bf16_t Vt[64 * 64];     // [d][key]
  __shared__ bf16_t Ps[4][16 * 64];  // per-wave P tile [q][key]

  const bf16_t* Qh = QKV + (size_t)b * S * QS + h * 64;
  const bf16_t* Kh = Qh + 1024;
  const bf16_t* Vh = Qh + 2048;
  bf16_t* Oh = O + (size_t)b * S * OS + h * 64;

  const int q0 = qt * 64 + wv * 16;

  bf16x8 qf[2];
#pragma unroll
  for (int c = 0; c < 2; ++c)
    qf[c] = *(const bf16x8*)(Qh + (size_t)(q0 + lr) * QS + c * 32 + lq * 8);

  float m_i[4], l_i[4];
  floatx4 o_acc[4];
#pragma unroll
  for (int i = 0; i < 4; ++i) {
    m_i[i] = -1e30f;
    l_i[i] = 0.f;
    o_acc[i] = (floatx4){0.f, 0.f, 0.f, 0.f};
  }

  const float* btab = bias_table + h * 2048;

  for (int kt = 0; kt < 16; ++kt) {
    const int k0 = kt * 64;
#pragma unroll
    for (int i = 0; i < 2; ++i) {
      int chunk = i * 256 + tid;
      int kr = chunk >> 3;
      int dc = (chunk & 7) * 8;
      *(bf16x8*)(Ks + kr * 64 + dc) =
          *(const bf16x8*)(Kh + (size_t)(k0 + kr) * QS + dc);
      bf16x8 vvv = *(const bf16x8*)(Vh + (size_t)(k0 + kr) * QS + dc);
#pragma unroll
      for (int j = 0; j < 8; ++j) Vt[(dc + j) * 64 + kr] = vvv[j];
    }
    __syncthreads();

    // S = Q K^T
    floatx4 s_acc[4];
#pragma unroll
    for (int g = 0; g < 4; ++g) {
      floatx4 a = (floatx4){0.f, 0.f, 0.f, 0.f};
#pragma unroll
      for (int c = 0; c < 2; ++c) {
        bf16x8 kf = *(const bf16x8*)(Ks + (g * 16 + lr) * 64 + c * 32 + lq * 8);
        a = __builtin_amdgcn_mfma_f32_16x16x32_bf16(qf[c], kf, a, 0, 0, 0);
      }
      s_acc[g] = a;
    }

    // + bias, row max.  lane holds S[q=q0+lq*4+t][key=k0+g*16+lr]
    float rowmax[4] = {-1e30f, -1e30f, -1e30f, -1e30f};
#pragma unroll
    for (int g = 0; g < 4; ++g) {
#pragma unroll
      for (int t = 0; t < 4; ++t) {
        int qg = q0 + lq * 4 + t;
        int kg = k0 + g * 16 + lr;
        float sv = s_acc[g][t] + btab[kg - qg + 1023];
        s_acc[g][t] = sv;
        rowmax[t] = fmaxf(rowmax[t], sv);
      }
    }
#pragma unroll
    for (int off = 1; off < 16; off <<= 1)
#pragma unroll
      for (int t = 0; t < 4; ++t)
        rowmax[t] = fmaxf(rowmax[t], __shfl_xor(rowmax[t], off));

    float alpha[4], rowsum[4];
#pragma unroll
    for (int t = 0; t < 4; ++t) {
      float mnew = fmaxf(m_i[t], rowmax[t]);
      alpha[t] = __expf(m_i[t] - mnew);
      m_i[t] = mnew;
      rowsum[t] = 0.f;
    }
#pragma unroll
    for (int g = 0; g < 4; ++g) {
#pragma unroll
      for (int t = 0; t < 4; ++t) {
        float p = __expf(s_acc[g][t] - m_i[t]);
        rowsum[t] += p;
        Ps[wv][(lq * 4 + t) * 64 + g * 16 + lr] = (bf16_t)p;
      }
    }
#pragma unroll
    for (int off = 1; off < 16; off <<= 1)
#pragma unroll
      for (int t = 0; t < 4; ++t) rowsum[t] += __shfl_xor(rowsum[t], off);
#pragma unroll
    for (int t = 0; t < 4; ++t) l_i[t] = l_i[t] * alpha[t] + rowsum[t];
#pragma unroll
    for (int g = 0; g < 4; ++g)
#pragma unroll
      for (int t = 0; t < 4; ++t) o_acc[g][t] *= alpha[t];

    __syncthreads();  // P writes visible

    bf16x8 pf[2];
#pragma unroll
    for (int c = 0; c < 2; ++c)
      pf[c] = *(const bf16x8*)(&Ps[wv][lr * 64 + c * 32 + lq * 8]);

    // O += P @ V
#pragma unroll
    for (int g = 0; g < 4; ++g) {
#pragma unroll
      for (int c = 0; c < 2; ++c) {
        bf16x8 vf = *(const bf16x8*)(Vt + (g * 16 + lr) * 64 + c * 32 + lq * 8);
        o_acc[g] = __builtin_amdgcn_mfma_f32_16x16x32_bf16(pf[c], vf, o_acc[g], 0, 0, 0);
      }
    }
    __syncthreads();
  }

  float inv_l[4];
#pragma unroll
  for (int t = 0; t < 4; ++t) inv_l[t] = 1.f / l_i[t];
#pragma unroll
  for (int g = 0; g < 4; ++g) {
#pragma unroll
    for (int t = 0; t < 4; ++t) {
      int qg = q0 + lq * 4 + t;
      int d = g * 16 + lr;
      Oh[(size_t)qg * OS + d] = (bf16_t)(o_acc[g][t] * inv_l[t]);
    }
  }
}

// ---------------------------------------------------------------------------
extern "C" void kernel_launch(void* const* d_in, const int* in_sizes, int n_in,
                              void* d_out, int out_size, void* d_ws,
                              size_t ws_size, hipStream_t stream) {
  const float* hs = (const float*)d_in[0];       // [2,1024,1024] fp32
  const float* ln1_w = (const float*)d_in[1];    // [1024]
  const float* wq = (const float*)d_in[2];       // [1024,1024]
  const float* wk = (const float*)d_in[3];
  const float* wvv = (const float*)d_in[4];
  const float* wo = (const float*)d_in[5];       // [1024,1024]
  const float* rel_bias = (const float*)d_in[6]; // [32,16]
  const float* ln2_w = (const float*)d_in[7];
  const float* wi = (const float*)d_in[8];       // [4096,1024]
  const float* wo_ff = (const float*)d_in[9];    // [1024,4096]
  float* out = (float*)d_out;                    // [2,1024,1024] fp32

  const int M = 2048, D = 1024, FF = 4096;
  const size_t SL = (size_t)M * D * 2;     // 4 MB  (bf16 [2048,1024])
  const size_t QKVB = (size_t)M * 3072 * 2; // 12 MB
  const size_t F1B = (size_t)M * FF * 2;   // 16 MB
  const size_t BT = 16 * 2048 * 4;         // 128 KB

  // Full plan: btab | x | qkv | ctx | hbuf | y | f1 | part(4 slices)
  const size_t FULL_NEED = BT + SL + QKVB + SL + SL + SL + F1B + 4 * SL;
  // Compact plan (proven to fit: == round-3 guard 33,685,504 B):
  //   btab | A(4MB: x->ctx->hbuf) | B(12MB: qkv -> part(2 slices)+y) | f1
  const size_t COMPACT_NEED = BT + SL + QKVB + F1B;

  char* w = (char*)d_ws;
  float* btab;
  bf16_t *x, *qkv, *ctx, *hbuf, *y, *f1, *part;
  int wo_splits, ff_splits;
  if (ws_size >= FULL_NEED) {
    btab = (float*)w; w += BT;
    x = (bf16_t*)w;    w += SL;
    qkv = (bf16_t*)w;  w += QKVB;
    ctx = (bf16_t*)w;  w += SL;
    hbuf = (bf16_t*)w; w += SL;
    y = (bf16_t*)w;    w += SL;
    f1 = (bf16_t*)w;   w += F1B;
    part = (bf16_t*)w; w += 4 * SL;
    wo_splits = 2; ff_splits = 4;
  } else {
    if (ws_size < COMPACT_NEED) return;
    btab = (float*)w; w += BT;
    char* A = w;      w += SL;
    char* B = w;      w += QKVB;
    f1 = (bf16_t*)w;  w += F1B;
    x = (bf16_t*)A; ctx = (bf16_t*)A; hbuf = (bf16_t*)A;   // sequential reuse
    qkv = (bf16_t*)B;
    part = (bf16_t*)B;                 // after qkv dead (2 slices = 8 MB)
    y = (bf16_t*)(B + 2 * SL);         // after part_wo dead
    wo_splits = 2; ff_splits = 2;
  }

  bias_table_kernel<<<128, 256, 0, stream>>>(rel_bias, btab);
  rmsnorm_kernel<<<M, 256, 0, stream>>>(hs, ln1_w, x, 1);

  // Fused QKV: [2048,3072] = x @ [wq|wk|wv]^T,  384 blocks
  dim3 gqkv(M / BM, 3072 / BN, 1);
  gemm_bt_kernel<<<gqkv, 256, 0, stream>>>(x, wq, wk, wvv, qkv,
                                           M, D, D, 3072, 1024, 0);

  dim3 ga(16, 16, 2);
  attn_kernel<<<ga, 256, 0, stream>>>(qkv, btab, ctx);

  // WO with split-K -> partials, then reduce(+hs) -> hbuf
  dim3 gwo(M / BM, D / BN, wo_splits);
  gemm_bt_kernel<<<gwo, 256, 0, stream>>>(ctx, wo, wo, wo, part,
                                          M, D, D / wo_splits, D, 1 << 30, 0);
  reduce_kernel<<<1024, 256, 0, stream>>>(part, wo_splits, hs, nullptr,
                                          nullptr, hbuf);

  rmsnorm_kernel<<<M, 256, 0, stream>>>(hbuf, ln2_w, y, 0);

  // WI (relu) -> f1, 512 blocks
  dim3 gwi(M / BM, FF / BN, 1);
  gemm_bt_kernel<<<gwi, 256, 0, stream>>>(y, wi, wi, wi, f1,
                                          M, D, D, FF, 1 << 30, 2);

  // WO_FF with split-K -> partials, then reduce(+hbuf) -> out (fp32)
  dim3 gff(M / BM, D / BN, ff_splits);
  gemm_bt_kernel<<<gff, 256, 0, stream>>>(f1, wo_ff, wo_ff, wo_ff, part,
                                          M, FF, FF / ff_splits, D, 1 << 30, 0);
  reduce_kernel<<<1024, 256, 0, stream>>>(part, ff_splits, nullptr, hbuf,
                                          out, nullptr);
}

// Round 6
// 269.124 us; speedup vs baseline: 2.0594x; 1.1633x over previous
//
#include <hip/hip_runtime.h>
#include <hip/hip_bf16.h>
#include <math.h>

// T5 encoder block on MI355X (gfx950). B=2, S=1024, D_MODEL=1024, H=16,
// D_KV=64, D_FF=4096. Harness buffers fp32; internal bf16 MFMA, fp32 acc.
// ROUND 6: attention bank-conflict fix (global V-transpose + DMA dbuf
// staging, 1 barrier/tile, Ps stride 68), GEMM BM=64 retile (2x blocks),
// optional bf16 weight pre-conversion (full-ws plan), fused reduce+RMSNorm.

typedef __bf16 bf16_t;
typedef __attribute__((ext_vector_type(8))) __bf16 bf16x8;
typedef __attribute__((ext_vector_type(4))) __bf16 bf16x4;
typedef __attribute__((ext_vector_type(4))) float floatx4;

#define GLOBAL_AS(p) ((const __attribute__((address_space(1))) void*)(p))
#define LDS_AS(p)    ((__attribute__((address_space(3))) void*)(p))

// ---------------------------------------------------------------------------
// Weights fp32 -> bf16 (full-ws plan only). 12,582,912 elems, 8 per thread.
// wqkv_b packs [wq;wk;wv] as [3072,1024].
// ---------------------------------------------------------------------------
__global__ __launch_bounds__(256) void convert_w_kernel(
    const float* __restrict__ wq, const float* __restrict__ wk,
    const float* __restrict__ wv, const float* __restrict__ wo,
    const float* __restrict__ wi, const float* __restrict__ woff,
    bf16_t* __restrict__ wqkv_b, bf16_t* __restrict__ wo_b,
    bf16_t* __restrict__ wi_b, bf16_t* __restrict__ woff_b) {
  size_t idx = ((size_t)blockIdx.x * 256 + threadIdx.x) * 8;
  const float* src;
  bf16_t* dst;
  size_t off;
  if (idx < 3145728) {
    size_t sec = idx >> 20;
    src = sec == 0 ? wq : (sec == 1 ? wk : wv);
    dst = wqkv_b + (sec << 20);
    off = idx & 1048575;
  } else if (idx < 4194304) {
    src = wo; dst = wo_b; off = idx - 3145728;
  } else if (idx < 8388608) {
    src = wi; dst = wi_b; off = idx - 4194304;
  } else {
    src = woff; dst = woff_b; off = idx - 8388608;
  }
  float4 a = *(const float4*)(src + off);
  float4 b = *(const float4*)(src + off + 4);
  bf16x8 o;
  o[0] = (bf16_t)a.x; o[1] = (bf16_t)a.y; o[2] = (bf16_t)a.z; o[3] = (bf16_t)a.w;
  o[4] = (bf16_t)b.x; o[5] = (bf16_t)b.y; o[6] = (bf16_t)b.z; o[7] = (bf16_t)b.w;
  *(bf16x8*)(dst + off) = o;
}

// ---------------------------------------------------------------------------
// Relative-position bias table: table[h][dpos] = rel_bias[bucket(k-q)][h]
// ---------------------------------------------------------------------------
__global__ void bias_table_kernel(const float* __restrict__ rel_bias,
                                  float* __restrict__ table) {
  int idx = blockIdx.x * 256 + threadIdx.x;
  int h = idx >> 11;
  int dpos = idx & 2047;
  int delta = dpos - 1023;
  if (delta > 1023) delta = 1023;
  int side = (delta > 0) ? 16 : 0;
  int rp = (delta < 0) ? -delta : delta;
  int bucket;
  if (rp < 8) {
    bucket = side + rp;
  } else {
    float t3 = (logf((float)rp * 0.125f) / 2.7725887f) * 8.0f;
    int v = 8 + (int)t3;
    if (v > 15) v = 15;
    bucket = side + v;
  }
  table[idx] = rel_bias[bucket * 16 + h];
}

// ---------------------------------------------------------------------------
// RMSNorm (fp32 input), one block per row (D=1024), output bf16.
// ---------------------------------------------------------------------------
__global__ __launch_bounds__(256) void rmsnorm_kernel(
    const float* __restrict__ X, const float* __restrict__ w,
    bf16_t* __restrict__ Y) {
  const int D = 1024;
  int row = blockIdx.x;
  int t = threadIdx.x;
  float4 v = ((const float4*)(X + (size_t)row * D))[t];
  float f[4] = {v.x, v.y, v.z, v.w};
  float s = 0.f;
#pragma unroll
  for (int j = 0; j < 4; ++j) s += f[j] * f[j];
#pragma unroll
  for (int off = 32; off > 0; off >>= 1) s += __shfl_down(s, off);
  __shared__ float red[4];
  int lane = t & 63, wave = t >> 6;
  if (lane == 0) red[wave] = s;
  __syncthreads();
  float tot = red[0] + red[1] + red[2] + red[3];
  float scale = rsqrtf(tot * (1.0f / D) + 1e-6f);
  float4 wv4 = ((const float4*)w)[t];
  bf16x4 o;
  o[0] = (bf16_t)(f[0] * scale * wv4.x);
  o[1] = (bf16_t)(f[1] * scale * wv4.y);
  o[2] = (bf16_t)(f[2] * scale * wv4.z);
  o[3] = (bf16_t)(f[3] * scale * wv4.w);
  *(bf16x4*)(Y + (size_t)row * D + t * 4) = o;
}

// ---------------------------------------------------------------------------
// GEMM: C[M,N] = epilogue(A[M,K] @ W[N,K]^T over K-slice blockIdx.z).
// TBM in {64,128}, BN=128, BK=32, 4 waves (2x2), wave tile (TBM/2)x64.
// WF32: W is fp32 with 3-way select (QKV fusion); else bf16, DMA-staged.
// OP: 0 = store, 2 = relu-store.  Output bf16 at C + z*M*N.
// ---------------------------------------------------------------------------
template <int TBM, bool WF32, int OP>
__global__ __launch_bounds__(256, 2) void gemm_bt(
    const bf16_t* __restrict__ A, const void* __restrict__ W0,
    const void* __restrict__ W1, const void* __restrict__ W2,
    bf16_t* __restrict__ C, int M, int K_total, int klen, int N,
    int wsel_cols) {
  constexpr int MFRAG = TBM / 32;  // acc tiles in m per wave
  constexpr int ACH = TBM / 64;    // A chunks per thread
  __shared__ bf16_t As[TBM * 32];
  __shared__ bf16_t Bs[128 * 32];

  const int tid = threadIdx.x;
  const int lane = tid & 63;
  const int wv = tid >> 6;
  const int wm = wv & 1;
  const int wn = wv >> 1;
  const int lr = lane & 15;
  const int lq = lane >> 4;

  const size_t row0 = (size_t)blockIdx.x * TBM;
  const size_t col0 = (size_t)blockIdx.y * 128;
  const int k0 = blockIdx.z * klen;

  const void* Ws = W0;
  size_t wc0 = col0;
  if ((int)col0 >= wsel_cols) {
    if ((int)col0 < 2 * wsel_cols) { Ws = W1; wc0 = col0 - wsel_cols; }
    else { Ws = W2; wc0 = col0 - 2 * (size_t)wsel_cols; }
  }

  const bf16_t* Abase = A + row0 * K_total;
  bf16_t* Cs = C + (size_t)blockIdx.z * M * N;

  floatx4 acc[MFRAG][4] = {};

  for (int kt = k0; kt < k0 + klen; kt += 32) {
#pragma unroll
    for (int i = 0; i < ACH; ++i) {
      int chunk = i * 256 + tid;
      int r = chunk >> 2;
      int kc = (chunk & 3) << 3;
      __builtin_amdgcn_global_load_lds(
          GLOBAL_AS(Abase + (size_t)r * K_total + kt + kc),
          LDS_AS(As + (size_t)(i * 256 + wv * 64) * 8), 16, 0, 0);
    }
    if constexpr (WF32) {
      const float* Wbase = (const float*)Ws + wc0 * K_total;
#pragma unroll
      for (int i = 0; i < 2; ++i) {
        int chunk = i * 256 + tid;
        int r = chunk >> 2;
        int kc = (chunk & 3) << 3;
        const float* p = Wbase + (size_t)r * K_total + kt + kc;
        float4 f0 = *(const float4*)p;
        float4 f1v = *(const float4*)(p + 4);
        bf16x8 o;
        o[0] = (bf16_t)f0.x; o[1] = (bf16_t)f0.y;
        o[2] = (bf16_t)f0.z; o[3] = (bf16_t)f0.w;
        o[4] = (bf16_t)f1v.x; o[5] = (bf16_t)f1v.y;
        o[6] = (bf16_t)f1v.z; o[7] = (bf16_t)f1v.w;
        *(bf16x8*)(Bs + chunk * 8) = o;
      }
    } else {
      const bf16_t* Wbase = (const bf16_t*)Ws + wc0 * K_total;
#pragma unroll
      for (int i = 0; i < 2; ++i) {
        int chunk = i * 256 + tid;
        int r = chunk >> 2;
        int kc = (chunk & 3) << 3;
        __builtin_amdgcn_global_load_lds(
            GLOBAL_AS(Wbase + (size_t)r * K_total + kt + kc),
            LDS_AS(Bs + (size_t)(i * 256 + wv * 64) * 8), 16, 0, 0);
      }
    }
    __syncthreads();

    bf16x8 af[MFRAG], bfr[4];
#pragma unroll
    for (int mi = 0; mi < MFRAG; ++mi)
      af[mi] = *(const bf16x8*)(As + (wm * (TBM / 2) + mi * 16 + lr) * 32 + lq * 8);
#pragma unroll
    for (int nj = 0; nj < 4; ++nj)
      bfr[nj] = *(const bf16x8*)(Bs + (wn * 64 + nj * 16 + lr) * 32 + lq * 8);

#pragma unroll
    for (int mi = 0; mi < MFRAG; ++mi)
#pragma unroll
      for (int nj = 0; nj < 4; ++nj)
        acc[mi][nj] = __builtin_amdgcn_mfma_f32_16x16x32_bf16(
            af[mi], bfr[nj], acc[mi][nj], 0, 0, 0);
    __syncthreads();
  }

#pragma unroll
  for (int mi = 0; mi < MFRAG; ++mi) {
#pragma unroll
    for (int nj = 0; nj < 4; ++nj) {
      size_t r = row0 + wm * (TBM / 2) + mi * 16 + lq * 4;
      size_t c = col0 + wn * 64 + nj * 16 + lr;
#pragma unroll
      for (int t = 0; t < 4; ++t) {
        float v = acc[mi][nj][t];
        if (OP == 2) v = v > 0.f ? v : 0.f;
        Cs[(r + t) * N + c] = (bf16_t)v;
      }
    }
  }
}

// ---------------------------------------------------------------------------
// V transpose: qkv V-section [b,s,h,d] -> Vt_g[(b*16+h)*64 + d][s].
// Grid (16 s-tiles, 16 h, 2 b), 256 threads.  LDS tile stride 65 (odd) so
// column reads spread across all banks.
// ---------------------------------------------------------------------------
__global__ __launch_bounds__(256) void transpose_v_kernel(
    const bf16_t* __restrict__ QKV, bf16_t* __restrict__ VT) {
  __shared__ bf16_t T[64 * 65];
  const int s0 = blockIdx.x * 64;
  const int h = blockIdx.y;
  const int b = blockIdx.z;
  const int tid = threadIdx.x;

  const bf16_t* Vh = QKV + ((size_t)b * 1024) * 3072 + 2048 + h * 64;
#pragma unroll
  for (int i = 0; i < 2; ++i) {
    int c = i * 256 + tid;
    int r = c >> 3;
    int d8 = (c & 7) * 8;
    bf16x8 v = *(const bf16x8*)(Vh + (size_t)(s0 + r) * 3072 + d8);
#pragma unroll
    for (int j = 0; j < 8; ++j) T[r * 65 + d8 + j] = v[j];
  }
  __syncthreads();

  bf16_t* Og = VT + ((size_t)b * 16 + h) * 64 * 1024;
#pragma unroll
  for (int i = 0; i < 2; ++i) {
    int c = i * 256 + tid;
    int d = c >> 3;
    int s8 = (c & 7) * 8;
    bf16x8 o;
#pragma unroll
    for (int j = 0; j < 8; ++j) o[j] = T[(s8 + j) * 65 + d];
    *(bf16x8*)(Og + (size_t)d * 1024 + s0 + s8) = o;
  }
}

// ---------------------------------------------------------------------------
// Flash attention, T5 style (+rel-pos bias).  D_KV=64, S=1024.
// Q,K from qkv [2048,3072]; V^T from Vt_g [32*64,1024]; out ctx [2048,1024].
// Grid (16,16,2); 4 waves; wave owns 16 q rows.  Double-buffered DMA
// staging, ONE barrier per tile.  Ps stride 68 (conflict-free writes).
// ---------------------------------------------------------------------------
__device__ __forceinline__ void attn_stage(const bf16_t* Kh, const bf16_t* Vg,
                                           int k0, bf16_t* Ksb, bf16_t* Vtb,
                                           int tid, int wv) {
#pragma unroll
  for (int i = 0; i < 2; ++i) {
    int c = i * 256 + tid;
    int kr = c >> 3;
    int dc = (c & 7) * 8;
    __builtin_amdgcn_global_load_lds(
        GLOBAL_AS(Kh + (size_t)(k0 + kr) * 3072 + dc),
        LDS_AS(Ksb + (size_t)(i * 256 + wv * 64) * 8), 16, 0, 0);
  }
#pragma unroll
  for (int i = 0; i < 2; ++i) {
    int c = i * 256 + tid;
    int dd = c >> 3;
    int kc = (c & 7) * 8;
    __builtin_amdgcn_global_load_lds(
        GLOBAL_AS(Vg + (size_t)dd * 1024 + k0 + kc),
        LDS_AS(Vtb + (size_t)(i * 256 + wv * 64) * 8), 16, 0, 0);
  }
}

__global__ __launch_bounds__(256) void attn_kernel(
    const bf16_t* __restrict__ QKV, const bf16_t* __restrict__ VT,
    const float* __restrict__ bias_table, bf16_t* __restrict__ O) {
  const int qt = blockIdx.x;
  const int h = blockIdx.y;
  const int b = blockIdx.z;
  const int tid = threadIdx.x;
  const int lane = tid & 63;
  const int wv = tid >> 6;
  const int lr = lane & 15;
  const int lq = lane >> 4;

  __shared__ bf16_t Ks[2][64 * 64];   // [key][d]
  __shared__ bf16_t Vt[2][64 * 64];   // [d][key]
  __shared__ bf16_t Ps[4][16 * 68];   // per-wave P, stride 68

  const bf16_t* Qh = QKV + (size_t)b * 1024 * 3072 + h * 64;
  const bf16_t* Kh = Qh + 1024;
  const bf16_t* Vg = VT + ((size_t)b * 16 + h) * 64 * 1024;
  bf16_t* Oh = O + (size_t)b * 1024 * 1024 + h * 64;

  const int q0 = qt * 64 + wv * 16;

  bf16x8 qf[2];
#pragma unroll
  for (int c = 0; c < 2; ++c)
    qf[c] = *(const bf16x8*)(Qh + (size_t)(q0 + lr) * 3072 + c * 32 + lq * 8);

  float m_i[4], l_i[4];
  floatx4 o_acc[4];
#pragma unroll
  for (int i = 0; i < 4; ++i) {
    m_i[i] = -1e30f;
    l_i[i] = 0.f;
    o_acc[i] = (floatx4){0.f, 0.f, 0.f, 0.f};
  }

  const float* btab = bias_table + h * 2048;

  attn_stage(Kh, Vg, 0, Ks[0], Vt[0], tid, wv);
  __syncthreads();

  for (int kt = 0; kt < 16; ++kt) {
    const int k0 = kt * 64;
    if (kt < 15)
      attn_stage(Kh, Vg, k0 + 64, Ks[(kt + 1) & 1], Vt[(kt + 1) & 1], tid, wv);
    const bf16_t* Ksb = Ks[kt & 1];
    const bf16_t* Vtb = Vt[kt & 1];

    // S = Q K^T
    floatx4 s_acc[4];
#pragma unroll
    for (int g = 0; g < 4; ++g) {
      floatx4 a = (floatx4){0.f, 0.f, 0.f, 0.f};
#pragma unroll
      for (int c = 0; c < 2; ++c) {
        bf16x8 kf = *(const bf16x8*)(Ksb + (g * 16 + lr) * 64 + c * 32 + lq * 8);
        a = __builtin_amdgcn_mfma_f32_16x16x32_bf16(qf[c], kf, a, 0, 0, 0);
      }
      s_acc[g] = a;
    }

    // + bias; online softmax.  lane holds S[q=q0+lq*4+t][key=k0+g*16+lr]
    float rowmax[4] = {-1e30f, -1e30f, -1e30f, -1e30f};
#pragma unroll
    for (int g = 0; g < 4; ++g) {
#pragma unroll
      for (int t = 0; t < 4; ++t) {
        int qg = q0 + lq * 4 + t;
        int kg = k0 + g * 16 + lr;
        float sv = s_acc[g][t] + btab[kg - qg + 1023];
        s_acc[g][t] = sv;
        rowmax[t] = fmaxf(rowmax[t], sv);
      }
    }
#pragma unroll
    for (int off = 1; off < 16; off <<= 1)
#pragma unroll
      for (int t = 0; t < 4; ++t)
        rowmax[t] = fmaxf(rowmax[t], __shfl_xor(rowmax[t], off));

    float alpha[4], rowsum[4];
#pragma unroll
    for (int t = 0; t < 4; ++t) {
      float mnew = fmaxf(m_i[t], rowmax[t]);
      alpha[t] = __expf(m_i[t] - mnew);
      m_i[t] = mnew;
      rowsum[t] = 0.f;
    }
#pragma unroll
    for (int g = 0; g < 4; ++g) {
#pragma unroll
      for (int t = 0; t < 4; ++t) {
        float p = __expf(s_acc[g][t] - m_i[t]);
        rowsum[t] += p;
        Ps[wv][(lq * 4 + t) * 68 + g * 16 + lr] = (bf16_t)p;
      }
    }
#pragma unroll
    for (int off = 1; off < 16; off <<= 1)
#pragma unroll
      for (int t = 0; t < 4; ++t) rowsum[t] += __shfl_xor(rowsum[t], off);
#pragma unroll
    for (int t = 0; t < 4; ++t) l_i[t] = l_i[t] * alpha[t] + rowsum[t];
#pragma unroll
    for (int g = 0; g < 4; ++g)
#pragma unroll
      for (int t = 0; t < 4; ++t) o_acc[g][t] *= alpha[t];

    // wave-local LDS RAW: DS ops are wave-FIFO; drain before re-reading Ps
    asm volatile("s_waitcnt lgkmcnt(0)" ::: "memory");

    bf16x8 pf[2];
#pragma unroll
    for (int c = 0; c < 2; ++c)
      pf[c] = *(const bf16x8*)(&Ps[wv][lr * 68 + c * 32 + lq * 8]);

    // O += P @ V
#pragma unroll
    for (int g = 0; g < 4; ++g) {
#pragma unroll
      for (int c = 0; c < 2; ++c) {
        bf16x8 vf = *(const bf16x8*)(Vtb + (g * 16 + lr) * 64 + c * 32 + lq * 8);
        o_acc[g] = __builtin_amdgcn_mfma_f32_16x16x32_bf16(pf[c], vf, o_acc[g], 0, 0, 0);
      }
    }
    __syncthreads();  // joins: PV reads done, next-tile DMA drained
  }

  float inv_l[4];
#pragma unroll
  for (int t = 0; t < 4; ++t) inv_l[t] = 1.f / l_i[t];
#pragma unroll
  for (int g = 0; g < 4; ++g) {
#pragma unroll
    for (int t = 0; t < 4; ++t) {
      int qg = q0 + lq * 4 + t;
      int d = g * 16 + lr;
      Oh[(size_t)qg * 1024 + d] = (bf16_t)(o_acc[g][t] * inv_l[t]);
    }
  }
}

// ---------------------------------------------------------------------------
// Split-K reduce + fp32 residual + fused RMSNorm.  Block = 2048 elems =
// 2 rows; writes hbuf (h, bf16) and y = rmsnorm(h)*ln2_w (bf16).
// ---------------------------------------------------------------------------
__global__ __launch_bounds__(256) void reduce_rms_kernel(
    const bf16_t* __restrict__ part, int splits, const float* __restrict__ hs,
    const float* __restrict__ ln2w, bf16_t* __restrict__ hbuf,
    bf16_t* __restrict__ y) {
  const size_t SLICE = (size_t)2048 * 1024;
  int tid = threadIdx.x;
  size_t i = ((size_t)blockIdx.x * 256 + tid) * 8;

  float s[8] = {};
  for (int sp = 0; sp < splits; ++sp) {
    bf16x8 p = *(const bf16x8*)(part + sp * SLICE + i);
#pragma unroll
    for (int j = 0; j < 8; ++j) s[j] += (float)p[j];
  }
  float4 a = *(const float4*)(hs + i);
  float4 b = *(const float4*)(hs + i + 4);
  s[0] += a.x; s[1] += a.y; s[2] += a.z; s[3] += a.w;
  s[4] += b.x; s[5] += b.y; s[6] += b.z; s[7] += b.w;

  bf16x8 hb;
#pragma unroll
  for (int j = 0; j < 8; ++j) hb[j] = (bf16_t)s[j];
  *(bf16x8*)(hbuf + i) = hb;

  float ss = 0.f;
#pragma unroll
  for (int j = 0; j < 8; ++j) ss += s[j] * s[j];
#pragma unroll
  for (int off = 32; off > 0; off >>= 1) ss += __shfl_down(ss, off);
  __shared__ float red[4];
  int wave = tid >> 6;
  if ((tid & 63) == 0) red[wave] = ss;
  __syncthreads();
  float rowss = (tid < 128) ? (red[0] + red[1]) : (red[2] + red[3]);
  float scale = rsqrtf(rowss * (1.f / 1024.f) + 1e-6f);

  int col = (int)(i & 1023);
  float4 w0 = *(const float4*)(ln2w + col);
  float4 w1 = *(const float4*)(ln2w + col + 4);
  bf16x8 o;
  o[0] = (bf16_t)(s[0] * scale * w0.x); o[1] = (bf16_t)(s[1] * scale * w0.y);
  o[2] = (bf16_t)(s[2] * scale * w0.z); o[3] = (bf16_t)(s[3] * scale * w0.w);
  o[4] = (bf16_t)(s[4] * scale * w1.x); o[5] = (bf16_t)(s[5] * scale * w1.y);
  o[6] = (bf16_t)(s[6] * scale * w1.z); o[7] = (bf16_t)(s[7] * scale * w1.w);
  *(bf16x8*)(y + i) = o;
}

// ---------------------------------------------------------------------------
// Final split-K reduce + bf16 residual -> fp32 output.
// ---------------------------------------------------------------------------
__global__ __launch_bounds__(256) void reduce_out_kernel(
    const bf16_t* __restrict__ part, int splits,
    const bf16_t* __restrict__ res, float* __restrict__ out) {
  const size_t SLICE = (size_t)2048 * 1024;
  size_t i = ((size_t)blockIdx.x * 256 + threadIdx.x) * 8;
  float s[8] = {};
  for (int sp = 0; sp < splits; ++sp) {
    bf16x8 p = *(const bf16x8*)(part + sp * SLICE + i);
#pragma unroll
    for (int j = 0; j < 8; ++j) s[j] += (float)p[j];
  }
  bf16x8 r = *(const bf16x8*)(res + i);
#pragma unroll
  for (int j = 0; j < 8; ++j) s[j] += (float)r[j];
  float4 a, b;
  a.x = s[0]; a.y = s[1]; a.z = s[2]; a.w = s[3];
  b.x = s[4]; b.y = s[5]; b.z = s[6]; b.w = s[7];
  *(float4*)(out + i) = a;
  *(float4*)(out + i + 4) = b;
}

// ---------------------------------------------------------------------------
extern "C" void kernel_launch(void* const* d_in, const int* in_sizes, int n_in,
                              void* d_out, int out_size, void* d_ws,
                              size_t ws_size, hipStream_t stream) {
  const float* hs = (const float*)d_in[0];
  const float* ln1_w = (const float*)d_in[1];
  const float* wq = (const float*)d_in[2];
  const float* wk = (const float*)d_in[3];
  const float* wvv = (const float*)d_in[4];
  const float* wo = (const float*)d_in[5];
  const float* rel_bias = (const float*)d_in[6];
  const float* ln2_w = (const float*)d_in[7];
  const float* wi = (const float*)d_in[8];
  const float* wo_ff = (const float*)d_in[9];
  float* out = (float*)d_out;

  const int M = 2048, D = 1024, FF = 4096;
  const size_t SL = (size_t)M * D * 2;       // 4 MB
  const size_t QKVB = (size_t)M * 3072 * 2;  // 12 MB
  const size_t F1B = (size_t)M * FF * 2;     // 16 MB
  const size_t BT = 16 * 2048 * 4;           // 128 KB

  // FULL: +bf16 weights, 4 partial slices, dedicated buffers (92.4 MB)
  const size_t FULL_NEED = BT + 6291456 + 2097152 + 8388608 + 8388608 +
                           SL + QKVB + SL + SL + SL + F1B + SL + 4 * SL;
  // COMPACT: exactly 33,685,504 B (proven available in round 3)
  const size_t COMPACT_NEED = BT + SL + QKVB + F1B;

  char* w = (char*)d_ws;
  dim3 gqkv(32, 24, 1), gwo, gwi(32, 32, 1), gff, gtv(16, 16, 2), ga(16, 16, 2);

  if (ws_size >= FULL_NEED) {
    float* btab = (float*)w;      w += BT;
    bf16_t* wqkv_b = (bf16_t*)w;  w += 6291456;
    bf16_t* wo_b = (bf16_t*)w;    w += 2097152;
    bf16_t* wi_b = (bf16_t*)w;    w += 8388608;
    bf16_t* woff_b = (bf16_t*)w;  w += 8388608;
    bf16_t* x = (bf16_t*)w;       w += SL;
    bf16_t* qkv = (bf16_t*)w;     w += QKVB;
    bf16_t* ctx = (bf16_t*)w;     w += SL;
    bf16_t* hbuf = (bf16_t*)w;    w += SL;
    bf16_t* y = (bf16_t*)w;       w += SL;
    bf16_t* f1 = (bf16_t*)w;      w += F1B;
    bf16_t* vtg = (bf16_t*)w;     w += SL;
    bf16_t* part = (bf16_t*)w;    w += 4 * SL;

    convert_w_kernel<<<6144, 256, 0, stream>>>(wq, wk, wvv, wo, wi, wo_ff,
                                               wqkv_b, wo_b, wi_b, woff_b);
    bias_table_kernel<<<128, 256, 0, stream>>>(rel_bias, btab);
    rmsnorm_kernel<<<M, 256, 0, stream>>>(hs, ln1_w, x);

    gemm_bt<64, false, 0><<<gqkv, 256, 0, stream>>>(
        x, wqkv_b, wqkv_b, wqkv_b, qkv, M, D, D, 3072, 1 << 30);
    transpose_v_kernel<<<gtv, 256, 0, stream>>>(qkv, vtg);
    attn_kernel<<<ga, 256, 0, stream>>>(qkv, vtg, btab, ctx);

    gwo = dim3(32, 8, 2);
    gemm_bt<64, false, 0><<<gwo, 256, 0, stream>>>(
        ctx, wo_b, wo_b, wo_b, part, M, D, D / 2, D, 1 << 30);
    reduce_rms_kernel<<<1024, 256, 0, stream>>>(part, 2, hs, ln2_w, hbuf, y);

    gemm_bt<64, false, 2><<<gwi, 256, 0, stream>>>(
        y, wi_b, wi_b, wi_b, f1, M, D, D, FF, 1 << 30);

    gff = dim3(32, 8, 4);
    gemm_bt<64, false, 0><<<gff, 256, 0, stream>>>(
        f1, woff_b, woff_b, woff_b, part, M, FF, FF / 4, D, 1 << 30);
    reduce_out_kernel<<<1024, 256, 0, stream>>>(part, 4, hbuf, out);
  } else {
    if (ws_size < COMPACT_NEED) return;
    float* btab = (float*)w;  w += BT;
    char* Abuf = w;           w += SL;
    char* Bbuf = w;           w += QKVB;
    char* Fbuf = w;           w += F1B;
    bf16_t* x = (bf16_t*)Abuf;
    bf16_t* ctx = (bf16_t*)Abuf;
    bf16_t* hbuf = (bf16_t*)Abuf;        // sequential reuse
    bf16_t* qkv = (bf16_t*)Bbuf;
    bf16_t* part = (bf16_t*)Bbuf;        // after qkv dead (2 slices)
    bf16_t* y = (bf16_t*)(Bbuf + 2 * SL);
    bf16_t* vtg = (bf16_t*)Fbuf;         // f1 region, dead until WI
    bf16_t* f1 = (bf16_t*)Fbuf;

    bias_table_kernel<<<128, 256, 0, stream>>>(rel_bias, btab);
    rmsnorm_kernel<<<M, 256, 0, stream>>>(hs, ln1_w, x);

    gemm_bt<64, true, 0><<<gqkv, 256, 0, stream>>>(
        x, wq, wk, wvv, qkv, M, D, D, 3072, 1024);
    transpose_v_kernel<<<gtv, 256, 0, stream>>>(qkv, vtg);
    attn_kernel<<<ga, 256, 0, stream>>>(qkv, vtg, btab, ctx);

    gwo = dim3(32, 8, 2);
    gemm_bt<64, true, 0><<<gwo, 256, 0, stream>>>(
        ctx, wo, wo, wo, part, M, D, D / 2, D, 1 << 30);
    reduce_rms_kernel<<<1024, 256, 0, stream>>>(part, 2, hs, ln2_w, hbuf, y);

    gemm_bt<64, true, 2><<<gwi, 256, 0, stream>>>(
        y, wi, wi, wi, f1, M, D, D, FF, 1 << 30);

    gff = dim3(32, 8, 2);
    gemm_bt<64, true, 0><<<gff, 256, 0, stream>>>(
        f1, wo_ff, wo_ff, wo_ff, part, M, FF, FF / 2, D, 1 << 30);
    reduce_out_kernel<<<1024, 256, 0, stream>>>(part, 2, hbuf, out);
  }
}

// Round 7
// 249.243 us; speedup vs baseline: 2.2237x; 1.0798x over previous
//
#include <hip/hip_runtime.h>
#include <hip/hip_bf16.h>
#include <math.h>

// T5 encoder block on MI355X (gfx950). B=2, S=1024, D_MODEL=1024, H=16,
// D_KV=64, D_FF=4096. Harness buffers fp32; internal bf16 MFMA, fp32 acc.
// ROUND 7: attention conflict elimination — fragment-major LDS for K/V/P
// (all ds accesses linear in lane), S^T MFMA (operand swap) so each lane
// owns one q-row, constant-shift softmax (exp(S-32), single end reduce).

typedef __bf16 bf16_t;
typedef __attribute__((ext_vector_type(8))) __bf16 bf16x8;
typedef __attribute__((ext_vector_type(4))) __bf16 bf16x4;
typedef __attribute__((ext_vector_type(4))) float floatx4;

#define GLOBAL_AS(p) ((const __attribute__((address_space(1))) void*)(p))
#define LDS_AS(p)    ((__attribute__((address_space(3))) void*)(p))

// ---------------------------------------------------------------------------
// Weights fp32 -> bf16 (full-ws plan only). wqkv_b packs [wq;wk;wv].
// ---------------------------------------------------------------------------
__global__ __launch_bounds__(256) void convert_w_kernel(
    const float* __restrict__ wq, const float* __restrict__ wk,
    const float* __restrict__ wv, const float* __restrict__ wo,
    const float* __restrict__ wi, const float* __restrict__ woff,
    bf16_t* __restrict__ wqkv_b, bf16_t* __restrict__ wo_b,
    bf16_t* __restrict__ wi_b, bf16_t* __restrict__ woff_b) {
  size_t idx = ((size_t)blockIdx.x * 256 + threadIdx.x) * 8;
  const float* src;
  bf16_t* dst;
  size_t off;
  if (idx < 3145728) {
    size_t sec = idx >> 20;
    src = sec == 0 ? wq : (sec == 1 ? wk : wv);
    dst = wqkv_b + (sec << 20);
    off = idx & 1048575;
  } else if (idx < 4194304) {
    src = wo; dst = wo_b; off = idx - 3145728;
  } else if (idx < 8388608) {
    src = wi; dst = wi_b; off = idx - 4194304;
  } else {
    src = woff; dst = woff_b; off = idx - 8388608;
  }
  float4 a = *(const float4*)(src + off);
  float4 b = *(const float4*)(src + off + 4);
  bf16x8 o;
  o[0] = (bf16_t)a.x; o[1] = (bf16_t)a.y; o[2] = (bf16_t)a.z; o[3] = (bf16_t)a.w;
  o[4] = (bf16_t)b.x; o[5] = (bf16_t)b.y; o[6] = (bf16_t)b.z; o[7] = (bf16_t)b.w;
  *(bf16x8*)(dst + off) = o;
}

// ---------------------------------------------------------------------------
// Relative-position bias table: table[h][dpos] = rel_bias[bucket(k-q)][h]
// ---------------------------------------------------------------------------
__global__ void bias_table_kernel(const float* __restrict__ rel_bias,
                                  float* __restrict__ table) {
  int idx = blockIdx.x * 256 + threadIdx.x;
  int h = idx >> 11;
  int dpos = idx & 2047;
  int delta = dpos - 1023;
  if (delta > 1023) delta = 1023;
  int side = (delta > 0) ? 16 : 0;
  int rp = (delta < 0) ? -delta : delta;
  int bucket;
  if (rp < 8) {
    bucket = side + rp;
  } else {
    float t3 = (logf((float)rp * 0.125f) / 2.7725887f) * 8.0f;
    int v = 8 + (int)t3;
    if (v > 15) v = 15;
    bucket = side + v;
  }
  table[idx] = rel_bias[bucket * 16 + h];
}

// ---------------------------------------------------------------------------
// RMSNorm (fp32 input), one block per row (D=1024), output bf16.
// ---------------------------------------------------------------------------
__global__ __launch_bounds__(256) void rmsnorm_kernel(
    const float* __restrict__ X, const float* __restrict__ w,
    bf16_t* __restrict__ Y) {
  const int D = 1024;
  int row = blockIdx.x;
  int t = threadIdx.x;
  float4 v = ((const float4*)(X + (size_t)row * D))[t];
  float f[4] = {v.x, v.y, v.z, v.w};
  float s = 0.f;
#pragma unroll
  for (int j = 0; j < 4; ++j) s += f[j] * f[j];
#pragma unroll
  for (int off = 32; off > 0; off >>= 1) s += __shfl_down(s, off);
  __shared__ float red[4];
  int lane = t & 63, wave = t >> 6;
  if (lane == 0) red[wave] = s;
  __syncthreads();
  float tot = red[0] + red[1] + red[2] + red[3];
  float scale = rsqrtf(tot * (1.0f / D) + 1e-6f);
  float4 wv4 = ((const float4*)w)[t];
  bf16x4 o;
  o[0] = (bf16_t)(f[0] * scale * wv4.x);
  o[1] = (bf16_t)(f[1] * scale * wv4.y);
  o[2] = (bf16_t)(f[2] * scale * wv4.z);
  o[3] = (bf16_t)(f[3] * scale * wv4.w);
  *(bf16x4*)(Y + (size_t)row * D + t * 4) = o;
}

// ---------------------------------------------------------------------------
// GEMM: C[M,N] = epilogue(A[M,K] @ W[N,K]^T over K-slice blockIdx.z).
// TBM in {64,128}, BN=128, BK=32, 4 waves (2x2).
// ---------------------------------------------------------------------------
template <int TBM, bool WF32, int OP>
__global__ __launch_bounds__(256, 2) void gemm_bt(
    const bf16_t* __restrict__ A, const void* __restrict__ W0,
    const void* __restrict__ W1, const void* __restrict__ W2,
    bf16_t* __restrict__ C, int M, int K_total, int klen, int N,
    int wsel_cols) {
  constexpr int MFRAG = TBM / 32;
  constexpr int ACH = TBM / 64;
  __shared__ bf16_t As[TBM * 32];
  __shared__ bf16_t Bs[128 * 32];

  const int tid = threadIdx.x;
  const int lane = tid & 63;
  const int wv = tid >> 6;
  const int wm = wv & 1;
  const int wn = wv >> 1;
  const int lr = lane & 15;
  const int lq = lane >> 4;

  const size_t row0 = (size_t)blockIdx.x * TBM;
  const size_t col0 = (size_t)blockIdx.y * 128;
  const int k0 = blockIdx.z * klen;

  const void* Ws = W0;
  size_t wc0 = col0;
  if ((int)col0 >= wsel_cols) {
    if ((int)col0 < 2 * wsel_cols) { Ws = W1; wc0 = col0 - wsel_cols; }
    else { Ws = W2; wc0 = col0 - 2 * (size_t)wsel_cols; }
  }

  const bf16_t* Abase = A + row0 * K_total;
  bf16_t* Cs = C + (size_t)blockIdx.z * M * N;

  floatx4 acc[MFRAG][4] = {};

  for (int kt = k0; kt < k0 + klen; kt += 32) {
#pragma unroll
    for (int i = 0; i < ACH; ++i) {
      int chunk = i * 256 + tid;
      int r = chunk >> 2;
      int kc = (chunk & 3) << 3;
      __builtin_amdgcn_global_load_lds(
          GLOBAL_AS(Abase + (size_t)r * K_total + kt + kc),
          LDS_AS(As + (size_t)(i * 256 + wv * 64) * 8), 16, 0, 0);
    }
    if constexpr (WF32) {
      const float* Wbase = (const float*)Ws + wc0 * K_total;
#pragma unroll
      for (int i = 0; i < 2; ++i) {
        int chunk = i * 256 + tid;
        int r = chunk >> 2;
        int kc = (chunk & 3) << 3;
        const float* p = Wbase + (size_t)r * K_total + kt + kc;
        float4 f0 = *(const float4*)p;
        float4 f1v = *(const float4*)(p + 4);
        bf16x8 o;
        o[0] = (bf16_t)f0.x; o[1] = (bf16_t)f0.y;
        o[2] = (bf16_t)f0.z; o[3] = (bf16_t)f0.w;
        o[4] = (bf16_t)f1v.x; o[5] = (bf16_t)f1v.y;
        o[6] = (bf16_t)f1v.z; o[7] = (bf16_t)f1v.w;
        *(bf16x8*)(Bs + chunk * 8) = o;
      }
    } else {
      const bf16_t* Wbase = (const bf16_t*)Ws + wc0 * K_total;
#pragma unroll
      for (int i = 0; i < 2; ++i) {
        int chunk = i * 256 + tid;
        int r = chunk >> 2;
        int kc = (chunk & 3) << 3;
        __builtin_amdgcn_global_load_lds(
            GLOBAL_AS(Wbase + (size_t)r * K_total + kt + kc),
            LDS_AS(Bs + (size_t)(i * 256 + wv * 64) * 8), 16, 0, 0);
      }
    }
    __syncthreads();

    bf16x8 af[MFRAG], bfr[4];
#pragma unroll
    for (int mi = 0; mi < MFRAG; ++mi)
      af[mi] = *(const bf16x8*)(As + (wm * (TBM / 2) + mi * 16 + lr) * 32 + lq * 8);
#pragma unroll
    for (int nj = 0; nj < 4; ++nj)
      bfr[nj] = *(const bf16x8*)(Bs + (wn * 64 + nj * 16 + lr) * 32 + lq * 8);

#pragma unroll
    for (int mi = 0; mi < MFRAG; ++mi)
#pragma unroll
      for (int nj = 0; nj < 4; ++nj)
        acc[mi][nj] = __builtin_amdgcn_mfma_f32_16x16x32_bf16(
            af[mi], bfr[nj], acc[mi][nj], 0, 0, 0);
    __syncthreads();
  }

#pragma unroll
  for (int mi = 0; mi < MFRAG; ++mi) {
#pragma unroll
    for (int nj = 0; nj < 4; ++nj) {
      size_t r = row0 + wm * (TBM / 2) + mi * 16 + lq * 4;
      size_t c = col0 + wn * 64 + nj * 16 + lr;
#pragma unroll
      for (int t = 0; t < 4; ++t) {
        float v = acc[mi][nj][t];
        if (OP == 2) v = v > 0.f ? v : 0.f;
        Cs[(r + t) * N + c] = (bf16_t)v;
      }
    }
  }
}

// ---------------------------------------------------------------------------
// V transpose: qkv V-section [b,s,h,d] -> Vt_g[(b*16+h)*64 + d][s].
// ---------------------------------------------------------------------------
__global__ __launch_bounds__(256) void transpose_v_kernel(
    const bf16_t* __restrict__ QKV, bf16_t* __restrict__ VT) {
  __shared__ bf16_t T[64 * 65];
  const int s0 = blockIdx.x * 64;
  const int h = blockIdx.y;
  const int b = blockIdx.z;
  const int tid = threadIdx.x;

  const bf16_t* Vh = QKV + ((size_t)b * 1024) * 3072 + 2048 + h * 64;
#pragma unroll
  for (int i = 0; i < 2; ++i) {
    int c = i * 256 + tid;
    int r = c >> 3;
    int d8 = (c & 7) * 8;
    bf16x8 v = *(const bf16x8*)(Vh + (size_t)(s0 + r) * 3072 + d8);
#pragma unroll
    for (int j = 0; j < 8; ++j) T[r * 65 + d8 + j] = v[j];
  }
  __syncthreads();

  bf16_t* Og = VT + ((size_t)b * 16 + h) * 64 * 1024;
#pragma unroll
  for (int i = 0; i < 2; ++i) {
    int c = i * 256 + tid;
    int d = c >> 3;
    int s8 = (c & 7) * 8;
    bf16x8 o;
#pragma unroll
    for (int j = 0; j < 8; ++j) o[j] = T[(s8 + j) * 65 + d];
    *(bf16x8*)(Og + (size_t)d * 1024 + s0 + s8) = o;
  }
}

// ---------------------------------------------------------------------------
// Flash attention, T5 style.  Fragment-major LDS: tiles stored as 8 blocks
// of [lane 0..63][16B] matching MFMA fragment order exactly; staged by
// gather-DMA (per-lane global addr -> lds base + lane*16).  All ds_reads
// are linear in lane (conflict-free).
// Ks block (g,c): lane l <- K[key = k0+g*16+(l&15)][d = c*32+(l>>4)*8 ..+7]
// Vt block (g,c): lane l <- V^T[d = g*16+(l&15)][key = k0+c*32+(l>>4)*8 ..]
// S^T = mfma(K-frag, Q-frag): lane owns q = lr, keys g*16+lq*4+t.
// Constant-shift softmax: P = exp(S + bias - 32); l reduced once at end.
// ---------------------------------------------------------------------------
__device__ __forceinline__ void attn_stage(const bf16_t* Kh, const bf16_t* Vg,
                                           int k0, bf16_t* Ksb, bf16_t* Vtb,
                                           int tid, int wv) {
  const int l16 = tid & 15;
  const int lo8 = ((tid & 63) >> 4) * 8;
#pragma unroll
  for (int i = 0; i < 2; ++i) {
    int bi = wv * 2 + i;          // block 0..7
    int g = bi >> 1, c = bi & 1;
    __builtin_amdgcn_global_load_lds(
        GLOBAL_AS(Kh + (size_t)(k0 + g * 16 + l16) * 3072 + c * 32 + lo8),
        LDS_AS(Ksb + bi * 512), 16, 0, 0);
    __builtin_amdgcn_global_load_lds(
        GLOBAL_AS(Vg + (size_t)(g * 16 + l16) * 1024 + k0 + c * 32 + lo8),
        LDS_AS(Vtb + bi * 512), 16, 0, 0);
  }
}

__global__ __launch_bounds__(256) void attn_kernel(
    const bf16_t* __restrict__ QKV, const bf16_t* __restrict__ VT,
    const float* __restrict__ bias_table, bf16_t* __restrict__ O) {
  const int qt = blockIdx.x;
  const int h = blockIdx.y;
  const int b = blockIdx.z;
  const int tid = threadIdx.x;
  const int lane = tid & 63;
  const int wv = tid >> 6;
  const int lr = lane & 15;
  const int lq = lane >> 4;

  __shared__ bf16_t Ks[2][4096];
  __shared__ bf16_t Vt[2][4096];
  __shared__ bf16_t Ps[4][1024];   // per-wave P, fragment-major

  const bf16_t* Qh = QKV + (size_t)b * 1024 * 3072 + h * 64;
  const bf16_t* Kh = Qh + 1024;
  const bf16_t* Vg = VT + ((size_t)b * 16 + h) * 64 * 1024;
  bf16_t* Oh = O + (size_t)b * 1024 * 1024 + h * 64;

  const int q0w = qt * 64 + wv * 16;
  const int myq = q0w + lr;  // this lane's q row (S^T layout)

  bf16x8 qf[2];
#pragma unroll
  for (int c = 0; c < 2; ++c)
    qf[c] = *(const bf16x8*)(Qh + (size_t)(q0w + lr) * 3072 + c * 32 + lq * 8);

  float l_loc = 0.f;
  floatx4 o_acc[4];
#pragma unroll
  for (int i = 0; i < 4; ++i) o_acc[i] = (floatx4){0.f, 0.f, 0.f, 0.f};

  const float* btab = bias_table + h * 2048 + 1023 - myq;

  attn_stage(Kh, Vg, 0, Ks[0], Vt[0], tid, wv);
  __syncthreads();

  for (int kt = 0; kt < 16; ++kt) {
    const int k0 = kt * 64;
    if (kt < 15)
      attn_stage(Kh, Vg, k0 + 64, Ks[(kt + 1) & 1], Vt[(kt + 1) & 1], tid, wv);
    const bf16_t* Ksb = Ks[kt & 1];
    const bf16_t* Vtb = Vt[kt & 1];

    // S^T = K Q^T : lane holds S[key = k0+g*16+lq*4+t][q = myq]
    floatx4 s_acc[4];
#pragma unroll
    for (int g = 0; g < 4; ++g) {
      floatx4 a = (floatx4){0.f, 0.f, 0.f, 0.f};
#pragma unroll
      for (int c = 0; c < 2; ++c) {
        bf16x8 kf = *(const bf16x8*)(Ksb + (g * 2 + c) * 512 + lane * 8);
        a = __builtin_amdgcn_mfma_f32_16x16x32_bf16(kf, qf[c], a, 0, 0, 0);
      }
      s_acc[g] = a;
    }

    // P = exp(S + bias - 32); packed write into fragment-major Ps
#pragma unroll
    for (int g = 0; g < 4; ++g) {
      bf16x4 pb;
#pragma unroll
      for (int t = 0; t < 4; ++t) {
        int key = k0 + g * 16 + lq * 4 + t;
        float p = __expf(s_acc[g][t] + btab[key] - 32.0f);
        l_loc += p;
        pb[t] = (bf16_t)p;
      }
      int c = g >> 1;
      int dst = c * 512 + (((g & 1) * 2 + (lq >> 1)) * 16 + lr) * 8 + (lq & 1) * 4;
      *(bf16x4*)(&Ps[wv][dst]) = pb;
    }

    // wave-local DS RAW drain before re-reading Ps
    asm volatile("s_waitcnt lgkmcnt(0)" ::: "memory");

    bf16x8 pf[2];
#pragma unroll
    for (int c = 0; c < 2; ++c)
      pf[c] = *(const bf16x8*)(&Ps[wv][c * 512 + lane * 8]);

    // O += P @ V
#pragma unroll
    for (int g = 0; g < 4; ++g) {
#pragma unroll
      for (int c = 0; c < 2; ++c) {
        bf16x8 vf = *(const bf16x8*)(Vtb + (g * 2 + c) * 512 + lane * 8);
        o_acc[g] = __builtin_amdgcn_mfma_f32_16x16x32_bf16(pf[c], vf, o_acc[g], 0, 0, 0);
      }
    }
    __syncthreads();
  }

  // l: lanes with same lr hold disjoint key subsets -> reduce over lq
  l_loc += __shfl_xor(l_loc, 16);
  l_loc += __shfl_xor(l_loc, 32);
  float inv = 1.f / l_loc;

  float invt[4];
#pragma unroll
  for (int t = 0; t < 4; ++t) invt[t] = __shfl(inv, lq * 4 + t);

#pragma unroll
  for (int g = 0; g < 4; ++g) {
#pragma unroll
    for (int t = 0; t < 4; ++t) {
      int qg = q0w + lq * 4 + t;
      int d = g * 16 + lr;
      Oh[(size_t)qg * 1024 + d] = (bf16_t)(o_acc[g][t] * invt[t]);
    }
  }
}

// ---------------------------------------------------------------------------
// Split-K reduce + fp32 residual + fused RMSNorm.
// ---------------------------------------------------------------------------
__global__ __launch_bounds__(256) void reduce_rms_kernel(
    const bf16_t* __restrict__ part, int splits, const float* __restrict__ hs,
    const float* __restrict__ ln2w, bf16_t* __restrict__ hbuf,
    bf16_t* __restrict__ y) {
  const size_t SLICE = (size_t)2048 * 1024;
  int tid = threadIdx.x;
  size_t i = ((size_t)blockIdx.x * 256 + tid) * 8;

  float s[8] = {};
  for (int sp = 0; sp < splits; ++sp) {
    bf16x8 p = *(const bf16x8*)(part + sp * SLICE + i);
#pragma unroll
    for (int j = 0; j < 8; ++j) s[j] += (float)p[j];
  }
  float4 a = *(const float4*)(hs + i);
  float4 b = *(const float4*)(hs + i + 4);
  s[0] += a.x; s[1] += a.y; s[2] += a.z; s[3] += a.w;
  s[4] += b.x; s[5] += b.y; s[6] += b.z; s[7] += b.w;

  bf16x8 hb;
#pragma unroll
  for (int j = 0; j < 8; ++j) hb[j] = (bf16_t)s[j];
  *(bf16x8*)(hbuf + i) = hb;

  float ss = 0.f;
#pragma unroll
  for (int j = 0; j < 8; ++j) ss += s[j] * s[j];
#pragma unroll
  for (int off = 32; off > 0; off >>= 1) ss += __shfl_down(ss, off);
  __shared__ float red[4];
  int wave = tid >> 6;
  if ((tid & 63) == 0) red[wave] = ss;
  __syncthreads();
  float rowss = (tid < 128) ? (red[0] + red[1]) : (red[2] + red[3]);
  float scale = rsqrtf(rowss * (1.f / 1024.f) + 1e-6f);

  int col = (int)(i & 1023);
  float4 w0 = *(const float4*)(ln2w + col);
  float4 w1 = *(const float4*)(ln2w + col + 4);
  bf16x8 o;
  o[0] = (bf16_t)(s[0] * scale * w0.x); o[1] = (bf16_t)(s[1] * scale * w0.y);
  o[2] = (bf16_t)(s[2] * scale * w0.z); o[3] = (bf16_t)(s[3] * scale * w0.w);
  o[4] = (bf16_t)(s[4] * scale * w1.x); o[5] = (bf16_t)(s[5] * scale * w1.y);
  o[6] = (bf16_t)(s[6] * scale * w1.z); o[7] = (bf16_t)(s[7] * scale * w1.w);
  *(bf16x8*)(y + i) = o;
}

// ---------------------------------------------------------------------------
// Final split-K reduce + bf16 residual -> fp32 output.
// ---------------------------------------------------------------------------
__global__ __launch_bounds__(256) void reduce_out_kernel(
    const bf16_t* __restrict__ part, int splits,
    const bf16_t* __restrict__ res, float* __restrict__ out) {
  const size_t SLICE = (size_t)2048 * 1024;
  size_t i = ((size_t)blockIdx.x * 256 + threadIdx.x) * 8;
  float s[8] = {};
  for (int sp = 0; sp < splits; ++sp) {
    bf16x8 p = *(const bf16x8*)(part + sp * SLICE + i);
#pragma unroll
    for (int j = 0; j < 8; ++j) s[j] += (float)p[j];
  }
  bf16x8 r = *(const bf16x8*)(res + i);
#pragma unroll
  for (int j = 0; j < 8; ++j) s[j] += (float)r[j];
  float4 a, b;
  a.x = s[0]; a.y = s[1]; a.z = s[2]; a.w = s[3];
  b.x = s[4]; b.y = s[5]; b.z = s[6]; b.w = s[7];
  *(float4*)(out + i) = a;
  *(float4*)(out + i + 4) = b;
}

// ---------------------------------------------------------------------------
extern "C" void kernel_launch(void* const* d_in, const int* in_sizes, int n_in,
                              void* d_out, int out_size, void* d_ws,
                              size_t ws_size, hipStream_t stream) {
  const float* hs = (const float*)d_in[0];
  const float* ln1_w = (const float*)d_in[1];
  const float* wq = (const float*)d_in[2];
  const float* wk = (const float*)d_in[3];
  const float* wvv = (const float*)d_in[4];
  const float* wo = (const float*)d_in[5];
  const float* rel_bias = (const float*)d_in[6];
  const float* ln2_w = (const float*)d_in[7];
  const float* wi = (const float*)d_in[8];
  const float* wo_ff = (const float*)d_in[9];
  float* out = (float*)d_out;

  const int M = 2048, D = 1024, FF = 4096;
  const size_t SL = (size_t)M * D * 2;
  const size_t QKVB = (size_t)M * 3072 * 2;
  const size_t F1B = (size_t)M * FF * 2;
  const size_t BT = 16 * 2048 * 4;

  const size_t FULL_NEED = BT + 6291456 + 2097152 + 8388608 + 8388608 +
                           SL + QKVB + SL + SL + SL + F1B + SL + 4 * SL;
  const size_t COMPACT_NEED = BT + SL + QKVB + F1B;  // 33,685,504 (proven)

  char* w = (char*)d_ws;
  dim3 gqkv(32, 24, 1), gwo, gwi(32, 32, 1), gff, gtv(16, 16, 2), ga(16, 16, 2);

  if (ws_size >= FULL_NEED) {
    float* btab = (float*)w;      w += BT;
    bf16_t* wqkv_b = (bf16_t*)w;  w += 6291456;
    bf16_t* wo_b = (bf16_t*)w;    w += 2097152;
    bf16_t* wi_b = (bf16_t*)w;    w += 8388608;
    bf16_t* woff_b = (bf16_t*)w;  w += 8388608;
    bf16_t* x = (bf16_t*)w;       w += SL;
    bf16_t* qkv = (bf16_t*)w;     w += QKVB;
    bf16_t* ctx = (bf16_t*)w;     w += SL;
    bf16_t* hbuf = (bf16_t*)w;    w += SL;
    bf16_t* y = (bf16_t*)w;       w += SL;
    bf16_t* f1 = (bf16_t*)w;      w += F1B;
    bf16_t* vtg = (bf16_t*)w;     w += SL;
    bf16_t* part = (bf16_t*)w;    w += 4 * SL;

    convert_w_kernel<<<6144, 256, 0, stream>>>(wq, wk, wvv, wo, wi, wo_ff,
                                               wqkv_b, wo_b, wi_b, woff_b);
    bias_table_kernel<<<128, 256, 0, stream>>>(rel_bias, btab);
    rmsnorm_kernel<<<M, 256, 0, stream>>>(hs, ln1_w, x);

    gemm_bt<64, false, 0><<<gqkv, 256, 0, stream>>>(
        x, wqkv_b, wqkv_b, wqkv_b, qkv, M, D, D, 3072, 1 << 30);
    transpose_v_kernel<<<gtv, 256, 0, stream>>>(qkv, vtg);
    attn_kernel<<<ga, 256, 0, stream>>>(qkv, vtg, btab, ctx);

    gwo = dim3(32, 8, 2);
    gemm_bt<64, false, 0><<<gwo, 256, 0, stream>>>(
        ctx, wo_b, wo_b, wo_b, part, M, D, D / 2, D, 1 << 30);
    reduce_rms_kernel<<<1024, 256, 0, stream>>>(part, 2, hs, ln2_w, hbuf, y);

    gemm_bt<64, false, 2><<<gwi, 256, 0, stream>>>(
        y, wi_b, wi_b, wi_b, f1, M, D, D, FF, 1 << 30);

    gff = dim3(32, 8, 4);
    gemm_bt<64, false, 0><<<gff, 256, 0, stream>>>(
        f1, woff_b, woff_b, woff_b, part, M, FF, FF / 4, D, 1 << 30);
    reduce_out_kernel<<<1024, 256, 0, stream>>>(part, 4, hbuf, out);
  } else {
    if (ws_size < COMPACT_NEED) return;
    float* btab = (float*)w;  w += BT;
    char* Abuf = w;           w += SL;
    char* Bbuf = w;           w += QKVB;
    char* Fbuf = w;           w += F1B;
    bf16_t* x = (bf16_t*)Abuf;
    bf16_t* ctx = (bf16_t*)Abuf;
    bf16_t* hbuf = (bf16_t*)Abuf;
    bf16_t* qkv = (bf16_t*)Bbuf;
    bf16_t* part = (bf16_t*)Bbuf;
    bf16_t* y = (bf16_t*)(Bbuf + 2 * SL);
    bf16_t* vtg = (bf16_t*)Fbuf;
    bf16_t* f1 = (bf16_t*)Fbuf;

    bias_table_kernel<<<128, 256, 0, stream>>>(rel_bias, btab);
    rmsnorm_kernel<<<M, 256, 0, stream>>>(hs, ln1_w, x);

    gemm_bt<64, true, 0><<<gqkv, 256, 0, stream>>>(
        x, wq, wk, wvv, qkv, M, D, D, 3072, 1024);
    transpose_v_kernel<<<gtv, 256, 0, stream>>>(qkv, vtg);
    attn_kernel<<<ga, 256, 0, stream>>>(qkv, vtg, btab, ctx);

    gwo = dim3(32, 8, 2);
    gemm_bt<64, true, 0><<<gwo, 256, 0, stream>>>(
        ctx, wo, wo, wo, part, M, D, D / 2, D, 1 << 30);
    reduce_rms_kernel<<<1024, 256, 0, stream>>>(part, 2, hs, ln2_w, hbuf, y);

    gemm_bt<64, true, 2><<<gwi, 256, 0, stream>>>(
        y, wi, wi, wi, f1, M, D, D, FF, 1 << 30);

    gff = dim3(32, 8, 2);
    gemm_bt<64, true, 0><<<gff, 256, 0, stream>>>(
        f1, wo_ff, wo_ff, wo_ff, part, M, FF, FF / 2, D, 1 << 30);
    reduce_out_kernel<<<1024, 256, 0, stream>>>(part, 2, hbuf, out);
  }
}

// Round 8
// 247.843 us; speedup vs baseline: 2.2363x; 1.0056x over previous
//
#include <hip/hip_runtime.h>
#include <hip/hip_bf16.h>
#include <math.h>

// T5 encoder block on MI355X (gfx950). B=2, S=1024, D_MODEL=1024, H=16,
// D_KV=64, D_FF=4096. Harness buffers fp32 (ws = 256 MiB -> full plan).
// Internal bf16 MFMA, fp32 acc.
// ROUND 8: GEMM retile to 128x128 (m97 structure) now that grids are
// 384-512 blocks: QKV 128-tile, WI 128-tile, WO & WO_FF 128-tile split-K=4.

typedef __bf16 bf16_t;
typedef __attribute__((ext_vector_type(8))) __bf16 bf16x8;
typedef __attribute__((ext_vector_type(4))) __bf16 bf16x4;
typedef __attribute__((ext_vector_type(4))) float floatx4;

#define GLOBAL_AS(p) ((const __attribute__((address_space(1))) void*)(p))
#define LDS_AS(p)    ((__attribute__((address_space(3))) void*)(p))

// ---------------------------------------------------------------------------
// Weights fp32 -> bf16 (full-ws plan only). wqkv_b packs [wq;wk;wv].
// ---------------------------------------------------------------------------
__global__ __launch_bounds__(256) void convert_w_kernel(
    const float* __restrict__ wq, const float* __restrict__ wk,
    const float* __restrict__ wv, const float* __restrict__ wo,
    const float* __restrict__ wi, const float* __restrict__ woff,
    bf16_t* __restrict__ wqkv_b, bf16_t* __restrict__ wo_b,
    bf16_t* __restrict__ wi_b, bf16_t* __restrict__ woff_b) {
  size_t idx = ((size_t)blockIdx.x * 256 + threadIdx.x) * 8;
  const float* src;
  bf16_t* dst;
  size_t off;
  if (idx < 3145728) {
    size_t sec = idx >> 20;
    src = sec == 0 ? wq : (sec == 1 ? wk : wv);
    dst = wqkv_b + (sec << 20);
    off = idx & 1048575;
  } else if (idx < 4194304) {
    src = wo; dst = wo_b; off = idx - 3145728;
  } else if (idx < 8388608) {
    src = wi; dst = wi_b; off = idx - 4194304;
  } else {
    src = woff; dst = woff_b; off = idx - 8388608;
  }
  float4 a = *(const float4*)(src + off);
  float4 b = *(const float4*)(src + off + 4);
  bf16x8 o;
  o[0] = (bf16_t)a.x; o[1] = (bf16_t)a.y; o[2] = (bf16_t)a.z; o[3] = (bf16_t)a.w;
  o[4] = (bf16_t)b.x; o[5] = (bf16_t)b.y; o[6] = (bf16_t)b.z; o[7] = (bf16_t)b.w;
  *(bf16x8*)(dst + off) = o;
}

// ---------------------------------------------------------------------------
// Relative-position bias table: table[h][dpos] = rel_bias[bucket(k-q)][h]
// ---------------------------------------------------------------------------
__global__ void bias_table_kernel(const float* __restrict__ rel_bias,
                                  float* __restrict__ table) {
  int idx = blockIdx.x * 256 + threadIdx.x;
  int h = idx >> 11;
  int dpos = idx & 2047;
  int delta = dpos - 1023;
  if (delta > 1023) delta = 1023;
  int side = (delta > 0) ? 16 : 0;
  int rp = (delta < 0) ? -delta : delta;
  int bucket;
  if (rp < 8) {
    bucket = side + rp;
  } else {
    float t3 = (logf((float)rp * 0.125f) / 2.7725887f) * 8.0f;
    int v = 8 + (int)t3;
    if (v > 15) v = 15;
    bucket = side + v;
  }
  table[idx] = rel_bias[bucket * 16 + h];
}

// ---------------------------------------------------------------------------
// RMSNorm (fp32 input), one block per row (D=1024), output bf16.
// ---------------------------------------------------------------------------
__global__ __launch_bounds__(256) void rmsnorm_kernel(
    const float* __restrict__ X, const float* __restrict__ w,
    bf16_t* __restrict__ Y) {
  const int D = 1024;
  int row = blockIdx.x;
  int t = threadIdx.x;
  float4 v = ((const float4*)(X + (size_t)row * D))[t];
  float f[4] = {v.x, v.y, v.z, v.w};
  float s = 0.f;
#pragma unroll
  for (int j = 0; j < 4; ++j) s += f[j] * f[j];
#pragma unroll
  for (int off = 32; off > 0; off >>= 1) s += __shfl_down(s, off);
  __shared__ float red[4];
  int lane = t & 63, wave = t >> 6;
  if (lane == 0) red[wave] = s;
  __syncthreads();
  float tot = red[0] + red[1] + red[2] + red[3];
  float scale = rsqrtf(tot * (1.0f / D) + 1e-6f);
  float4 wv4 = ((const float4*)w)[t];
  bf16x4 o;
  o[0] = (bf16_t)(f[0] * scale * wv4.x);
  o[1] = (bf16_t)(f[1] * scale * wv4.y);
  o[2] = (bf16_t)(f[2] * scale * wv4.z);
  o[3] = (bf16_t)(f[3] * scale * wv4.w);
  *(bf16x4*)(Y + (size_t)row * D + t * 4) = o;
}

// ---------------------------------------------------------------------------
// GEMM: C[M,N] = epilogue(A[M,K] @ W[N,K]^T over K-slice blockIdx.z).
// TBM in {64,128}, BN=128, BK=32, 4 waves (2x2), wave tile (TBM/2)x64.
// WF32: W fp32 + 3-way select (compact QKV); else bf16 DMA staging.
// OP: 0 = store, 2 = relu-store.  Output bf16 at C + z*M*N.
// ---------------------------------------------------------------------------
template <int TBM, bool WF32, int OP>
__global__ __launch_bounds__(256, 2) void gemm_bt(
    const bf16_t* __restrict__ A, const void* __restrict__ W0,
    const void* __restrict__ W1, const void* __restrict__ W2,
    bf16_t* __restrict__ C, int M, int K_total, int klen, int N,
    int wsel_cols) {
  constexpr int MFRAG = TBM / 32;
  constexpr int ACH = TBM / 64;
  __shared__ bf16_t As[TBM * 32];
  __shared__ bf16_t Bs[128 * 32];

  const int tid = threadIdx.x;
  const int lane = tid & 63;
  const int wv = tid >> 6;
  const int wm = wv & 1;
  const int wn = wv >> 1;
  const int lr = lane & 15;
  const int lq = lane >> 4;

  const size_t row0 = (size_t)blockIdx.x * TBM;
  const size_t col0 = (size_t)blockIdx.y * 128;
  const int k0 = blockIdx.z * klen;

  const void* Ws = W0;
  size_t wc0 = col0;
  if ((int)col0 >= wsel_cols) {
    if ((int)col0 < 2 * wsel_cols) { Ws = W1; wc0 = col0 - wsel_cols; }
    else { Ws = W2; wc0 = col0 - 2 * (size_t)wsel_cols; }
  }

  const bf16_t* Abase = A + row0 * K_total;
  bf16_t* Cs = C + (size_t)blockIdx.z * M * N;

  floatx4 acc[MFRAG][4] = {};

  for (int kt = k0; kt < k0 + klen; kt += 32) {
#pragma unroll
    for (int i = 0; i < ACH; ++i) {
      int chunk = i * 256 + tid;
      int r = chunk >> 2;
      int kc = (chunk & 3) << 3;
      __builtin_amdgcn_global_load_lds(
          GLOBAL_AS(Abase + (size_t)r * K_total + kt + kc),
          LDS_AS(As + (size_t)(i * 256 + wv * 64) * 8), 16, 0, 0);
    }
    if constexpr (WF32) {
      const float* Wbase = (const float*)Ws + wc0 * K_total;
#pragma unroll
      for (int i = 0; i < 2; ++i) {
        int chunk = i * 256 + tid;
        int r = chunk >> 2;
        int kc = (chunk & 3) << 3;
        const float* p = Wbase + (size_t)r * K_total + kt + kc;
        float4 f0 = *(const float4*)p;
        float4 f1v = *(const float4*)(p + 4);
        bf16x8 o;
        o[0] = (bf16_t)f0.x; o[1] = (bf16_t)f0.y;
        o[2] = (bf16_t)f0.z; o[3] = (bf16_t)f0.w;
        o[4] = (bf16_t)f1v.x; o[5] = (bf16_t)f1v.y;
        o[6] = (bf16_t)f1v.z; o[7] = (bf16_t)f1v.w;
        *(bf16x8*)(Bs + chunk * 8) = o;
      }
    } else {
      const bf16_t* Wbase = (const bf16_t*)Ws + wc0 * K_total;
#pragma unroll
      for (int i = 0; i < 2; ++i) {
        int chunk = i * 256 + tid;
        int r = chunk >> 2;
        int kc = (chunk & 3) << 3;
        __builtin_amdgcn_global_load_lds(
            GLOBAL_AS(Wbase + (size_t)r * K_total + kt + kc),
            LDS_AS(Bs + (size_t)(i * 256 + wv * 64) * 8), 16, 0, 0);
      }
    }
    __syncthreads();

    bf16x8 af[MFRAG], bfr[4];
#pragma unroll
    for (int mi = 0; mi < MFRAG; ++mi)
      af[mi] = *(const bf16x8*)(As + (wm * (TBM / 2) + mi * 16 + lr) * 32 + lq * 8);
#pragma unroll
    for (int nj = 0; nj < 4; ++nj)
      bfr[nj] = *(const bf16x8*)(Bs + (wn * 64 + nj * 16 + lr) * 32 + lq * 8);

#pragma unroll
    for (int mi = 0; mi < MFRAG; ++mi)
#pragma unroll
      for (int nj = 0; nj < 4; ++nj)
        acc[mi][nj] = __builtin_amdgcn_mfma_f32_16x16x32_bf16(
            af[mi], bfr[nj], acc[mi][nj], 0, 0, 0);
    __syncthreads();
  }

#pragma unroll
  for (int mi = 0; mi < MFRAG; ++mi) {
#pragma unroll
    for (int nj = 0; nj < 4; ++nj) {
      size_t r = row0 + wm * (TBM / 2) + mi * 16 + lq * 4;
      size_t c = col0 + wn * 64 + nj * 16 + lr;
#pragma unroll
      for (int t = 0; t < 4; ++t) {
        float v = acc[mi][nj][t];
        if (OP == 2) v = v > 0.f ? v : 0.f;
        Cs[(r + t) * N + c] = (bf16_t)v;
      }
    }
  }
}

// ---------------------------------------------------------------------------
// V transpose: qkv V-section [b,s,h,d] -> Vt_g[(b*16+h)*64 + d][s].
// ---------------------------------------------------------------------------
__global__ __launch_bounds__(256) void transpose_v_kernel(
    const bf16_t* __restrict__ QKV, bf16_t* __restrict__ VT) {
  __shared__ bf16_t T[64 * 65];
  const int s0 = blockIdx.x * 64;
  const int h = blockIdx.y;
  const int b = blockIdx.z;
  const int tid = threadIdx.x;

  const bf16_t* Vh = QKV + ((size_t)b * 1024) * 3072 + 2048 + h * 64;
#pragma unroll
  for (int i = 0; i < 2; ++i) {
    int c = i * 256 + tid;
    int r = c >> 3;
    int d8 = (c & 7) * 8;
    bf16x8 v = *(const bf16x8*)(Vh + (size_t)(s0 + r) * 3072 + d8);
#pragma unroll
    for (int j = 0; j < 8; ++j) T[r * 65 + d8 + j] = v[j];
  }
  __syncthreads();

  bf16_t* Og = VT + ((size_t)b * 16 + h) * 64 * 1024;
#pragma unroll
  for (int i = 0; i < 2; ++i) {
    int c = i * 256 + tid;
    int d = c >> 3;
    int s8 = (c & 7) * 8;
    bf16x8 o;
#pragma unroll
    for (int j = 0; j < 8; ++j) o[j] = T[(s8 + j) * 65 + d];
    *(bf16x8*)(Og + (size_t)d * 1024 + s0 + s8) = o;
  }
}

// ---------------------------------------------------------------------------
// Flash attention, T5 style.  Fragment-major LDS (conflict-free), S^T MFMA,
// constant-shift softmax.  See round-7 comments.
// ---------------------------------------------------------------------------
__device__ __forceinline__ void attn_stage(const bf16_t* Kh, const bf16_t* Vg,
                                           int k0, bf16_t* Ksb, bf16_t* Vtb,
                                           int tid, int wv) {
  const int l16 = tid & 15;
  const int lo8 = ((tid & 63) >> 4) * 8;
#pragma unroll
  for (int i = 0; i < 2; ++i) {
    int bi = wv * 2 + i;
    int g = bi >> 1, c = bi & 1;
    __builtin_amdgcn_global_load_lds(
        GLOBAL_AS(Kh + (size_t)(k0 + g * 16 + l16) * 3072 + c * 32 + lo8),
        LDS_AS(Ksb + bi * 512), 16, 0, 0);
    __builtin_amdgcn_global_load_lds(
        GLOBAL_AS(Vg + (size_t)(g * 16 + l16) * 1024 + k0 + c * 32 + lo8),
        LDS_AS(Vtb + bi * 512), 16, 0, 0);
  }
}

__global__ __launch_bounds__(256) void attn_kernel(
    const bf16_t* __restrict__ QKV, const bf16_t* __restrict__ VT,
    const float* __restrict__ bias_table, bf16_t* __restrict__ O) {
  const int qt = blockIdx.x;
  const int h = blockIdx.y;
  const int b = blockIdx.z;
  const int tid = threadIdx.x;
  const int lane = tid & 63;
  const int wv = tid >> 6;
  const int lr = lane & 15;
  const int lq = lane >> 4;

  __shared__ bf16_t Ks[2][4096];
  __shared__ bf16_t Vt[2][4096];
  __shared__ bf16_t Ps[4][1024];

  const bf16_t* Qh = QKV + (size_t)b * 1024 * 3072 + h * 64;
  const bf16_t* Kh = Qh + 1024;
  const bf16_t* Vg = VT + ((size_t)b * 16 + h) * 64 * 1024;
  bf16_t* Oh = O + (size_t)b * 1024 * 1024 + h * 64;

  const int q0w = qt * 64 + wv * 16;
  const int myq = q0w + lr;

  bf16x8 qf[2];
#pragma unroll
  for (int c = 0; c < 2; ++c)
    qf[c] = *(const bf16x8*)(Qh + (size_t)(q0w + lr) * 3072 + c * 32 + lq * 8);

  float l_loc = 0.f;
  floatx4 o_acc[4];
#pragma unroll
  for (int i = 0; i < 4; ++i) o_acc[i] = (floatx4){0.f, 0.f, 0.f, 0.f};

  const float* btab = bias_table + h * 2048 + 1023 - myq;

  attn_stage(Kh, Vg, 0, Ks[0], Vt[0], tid, wv);
  __syncthreads();

  for (int kt = 0; kt < 16; ++kt) {
    const int k0 = kt * 64;
    if (kt < 15)
      attn_stage(Kh, Vg, k0 + 64, Ks[(kt + 1) & 1], Vt[(kt + 1) & 1], tid, wv);
    const bf16_t* Ksb = Ks[kt & 1];
    const bf16_t* Vtb = Vt[kt & 1];

    floatx4 s_acc[4];
#pragma unroll
    for (int g = 0; g < 4; ++g) {
      floatx4 a = (floatx4){0.f, 0.f, 0.f, 0.f};
#pragma unroll
      for (int c = 0; c < 2; ++c) {
        bf16x8 kf = *(const bf16x8*)(Ksb + (g * 2 + c) * 512 + lane * 8);
        a = __builtin_amdgcn_mfma_f32_16x16x32_bf16(kf, qf[c], a, 0, 0, 0);
      }
      s_acc[g] = a;
    }

#pragma unroll
    for (int g = 0; g < 4; ++g) {
      bf16x4 pb;
#pragma unroll
      for (int t = 0; t < 4; ++t) {
        int key = k0 + g * 16 + lq * 4 + t;
        float p = __expf(s_acc[g][t] + btab[key] - 32.0f);
        l_loc += p;
        pb[t] = (bf16_t)p;
      }
      int c = g >> 1;
      int dst = c * 512 + (((g & 1) * 2 + (lq >> 1)) * 16 + lr) * 8 + (lq & 1) * 4;
      *(bf16x4*)(&Ps[wv][dst]) = pb;
    }

    asm volatile("s_waitcnt lgkmcnt(0)" ::: "memory");

    bf16x8 pf[2];
#pragma unroll
    for (int c = 0; c < 2; ++c)
      pf[c] = *(const bf16x8*)(&Ps[wv][c * 512 + lane * 8]);

#pragma unroll
    for (int g = 0; g < 4; ++g) {
#pragma unroll
      for (int c = 0; c < 2; ++c) {
        bf16x8 vf = *(const bf16x8*)(Vtb + (g * 2 + c) * 512 + lane * 8);
        o_acc[g] = __builtin_amdgcn_mfma_f32_16x16x32_bf16(pf[c], vf, o_acc[g], 0, 0, 0);
      }
    }
    __syncthreads();
  }

  l_loc += __shfl_xor(l_loc, 16);
  l_loc += __shfl_xor(l_loc, 32);
  float inv = 1.f / l_loc;

  float invt[4];
#pragma unroll
  for (int t = 0; t < 4; ++t) invt[t] = __shfl(inv, lq * 4 + t);

#pragma unroll
  for (int g = 0; g < 4; ++g) {
#pragma unroll
    for (int t = 0; t < 4; ++t) {
      int qg = q0w + lq * 4 + t;
      int d = g * 16 + lr;
      Oh[(size_t)qg * 1024 + d] = (bf16_t)(o_acc[g][t] * invt[t]);
    }
  }
}

// ---------------------------------------------------------------------------
// Split-K reduce + fp32 residual + fused RMSNorm.
// ---------------------------------------------------------------------------
__global__ __launch_bounds__(256) void reduce_rms_kernel(
    const bf16_t* __restrict__ part, int splits, const float* __restrict__ hs,
    const float* __restrict__ ln2w, bf16_t* __restrict__ hbuf,
    bf16_t* __restrict__ y) {
  const size_t SLICE = (size_t)2048 * 1024;
  int tid = threadIdx.x;
  size_t i = ((size_t)blockIdx.x * 256 + tid) * 8;

  float s[8] = {};
  for (int sp = 0; sp < splits; ++sp) {
    bf16x8 p = *(const bf16x8*)(part + sp * SLICE + i);
#pragma unroll
    for (int j = 0; j < 8; ++j) s[j] += (float)p[j];
  }
  float4 a = *(const float4*)(hs + i);
  float4 b = *(const float4*)(hs + i + 4);
  s[0] += a.x; s[1] += a.y; s[2] += a.z; s[3] += a.w;
  s[4] += b.x; s[5] += b.y; s[6] += b.z; s[7] += b.w;

  bf16x8 hb;
#pragma unroll
  for (int j = 0; j < 8; ++j) hb[j] = (bf16_t)s[j];
  *(bf16x8*)(hbuf + i) = hb;

  float ss = 0.f;
#pragma unroll
  for (int j = 0; j < 8; ++j) ss += s[j] * s[j];
#pragma unroll
  for (int off = 32; off > 0; off >>= 1) ss += __shfl_down(ss, off);
  __shared__ float red[4];
  int wave = tid >> 6;
  if ((tid & 63) == 0) red[wave] = ss;
  __syncthreads();
  float rowss = (tid < 128) ? (red[0] + red[1]) : (red[2] + red[3]);
  float scale = rsqrtf(rowss * (1.f / 1024.f) + 1e-6f);

  int col = (int)(i & 1023);
  float4 w0 = *(const float4*)(ln2w + col);
  float4 w1 = *(const float4*)(ln2w + col + 4);
  bf16x8 o;
  o[0] = (bf16_t)(s[0] * scale * w0.x); o[1] = (bf16_t)(s[1] * scale * w0.y);
  o[2] = (bf16_t)(s[2] * scale * w0.z); o[3] = (bf16_t)(s[3] * scale * w0.w);
  o[4] = (bf16_t)(s[4] * scale * w1.x); o[5] = (bf16_t)(s[5] * scale * w1.y);
  o[6] = (bf16_t)(s[6] * scale * w1.z); o[7] = (bf16_t)(s[7] * scale * w1.w);
  *(bf16x8*)(y + i) = o;
}

// ---------------------------------------------------------------------------
// Final split-K reduce + bf16 residual -> fp32 output.
// ---------------------------------------------------------------------------
__global__ __launch_bounds__(256) void reduce_out_kernel(
    const bf16_t* __restrict__ part, int splits,
    const bf16_t* __restrict__ res, float* __restrict__ out) {
  const size_t SLICE = (size_t)2048 * 1024;
  size_t i = ((size_t)blockIdx.x * 256 + threadIdx.x) * 8;
  float s[8] = {};
  for (int sp = 0; sp < splits; ++sp) {
    bf16x8 p = *(const bf16x8*)(part + sp * SLICE + i);
#pragma unroll
    for (int j = 0; j < 8; ++j) s[j] += (float)p[j];
  }
  bf16x8 r = *(const bf16x8*)(res + i);
#pragma unroll
  for (int j = 0; j < 8; ++j) s[j] += (float)r[j];
  float4 a, b;
  a.x = s[0]; a.y = s[1]; a.z = s[2]; a.w = s[3];
  b.x = s[4]; b.y = s[5]; b.z = s[6]; b.w = s[7];
  *(float4*)(out + i) = a;
  *(float4*)(out + i + 4) = b;
}

// ---------------------------------------------------------------------------
extern "C" void kernel_launch(void* const* d_in, const int* in_sizes, int n_in,
                              void* d_out, int out_size, void* d_ws,
                              size_t ws_size, hipStream_t stream) {
  const float* hs = (const float*)d_in[0];
  const float* ln1_w = (const float*)d_in[1];
  const float* wq = (const float*)d_in[2];
  const float* wk = (const float*)d_in[3];
  const float* wvv = (const float*)d_in[4];
  const float* wo = (const float*)d_in[5];
  const float* rel_bias = (const float*)d_in[6];
  const float* ln2_w = (const float*)d_in[7];
  const float* wi = (const float*)d_in[8];
  const float* wo_ff = (const float*)d_in[9];
  float* out = (float*)d_out;

  const int M = 2048, D = 1024, FF = 4096;
  const size_t SL = (size_t)M * D * 2;
  const size_t QKVB = (size_t)M * 3072 * 2;
  const size_t F1B = (size_t)M * FF * 2;
  const size_t BT = 16 * 2048 * 4;

  const size_t FULL_NEED = BT + 6291456 + 2097152 + 8388608 + 8388608 +
                           SL + QKVB + SL + SL + SL + F1B + SL + 4 * SL;
  const size_t COMPACT_NEED = BT + SL + QKVB + F1B;  // 33,685,504 (proven)

  char* w = (char*)d_ws;
  dim3 gtv(16, 16, 2), ga(16, 16, 2);

  if (ws_size >= FULL_NEED) {
    float* btab = (float*)w;      w += BT;
    bf16_t* wqkv_b = (bf16_t*)w;  w += 6291456;
    bf16_t* wo_b = (bf16_t*)w;    w += 2097152;
    bf16_t* wi_b = (bf16_t*)w;    w += 8388608;
    bf16_t* woff_b = (bf16_t*)w;  w += 8388608;
    bf16_t* x = (bf16_t*)w;       w += SL;
    bf16_t* qkv = (bf16_t*)w;     w += QKVB;
    bf16_t* ctx = (bf16_t*)w;     w += SL;
    bf16_t* hbuf = (bf16_t*)w;    w += SL;
    bf16_t* y = (bf16_t*)w;       w += SL;
    bf16_t* f1 = (bf16_t*)w;      w += F1B;
    bf16_t* vtg = (bf16_t*)w;     w += SL;
    bf16_t* part = (bf16_t*)w;    w += 4 * SL;

    convert_w_kernel<<<6144, 256, 0, stream>>>(wq, wk, wvv, wo, wi, wo_ff,
                                               wqkv_b, wo_b, wi_b, woff_b);
    bias_table_kernel<<<128, 256, 0, stream>>>(rel_bias, btab);
    rmsnorm_kernel<<<M, 256, 0, stream>>>(hs, ln1_w, x);

    // QKV: 128-tile, (16,24) = 384 blocks
    gemm_bt<128, false, 0><<<dim3(16, 24, 1), 256, 0, stream>>>(
        x, wqkv_b, wqkv_b, wqkv_b, qkv, M, D, D, 3072, 1 << 30);
    transpose_v_kernel<<<gtv, 256, 0, stream>>>(qkv, vtg);
    attn_kernel<<<ga, 256, 0, stream>>>(qkv, vtg, btab, ctx);

    // WO: 128-tile split-K=4 -> (16,8,4) = 512 blocks, K=256 each
    gemm_bt<128, false, 0><<<dim3(16, 8, 4), 256, 0, stream>>>(
        ctx, wo_b, wo_b, wo_b, part, M, D, D / 4, D, 1 << 30);
    reduce_rms_kernel<<<1024, 256, 0, stream>>>(part, 4, hs, ln2_w, hbuf, y);

    // WI: 128-tile, (16,32) = 512 blocks
    gemm_bt<128, false, 2><<<dim3(16, 32, 1), 256, 0, stream>>>(
        y, wi_b, wi_b, wi_b, f1, M, D, D, FF, 1 << 30);

    // WO_FF: 128-tile split-K=4 -> 512 blocks, K=1024 each
    gemm_bt<128, false, 0><<<dim3(16, 8, 4), 256, 0, stream>>>(
        f1, woff_b, woff_b, woff_b, part, M, FF, FF / 4, D, 1 << 30);
    reduce_out_kernel<<<1024, 256, 0, stream>>>(part, 4, hbuf, out);
  } else {
    if (ws_size < COMPACT_NEED) return;
    float* btab = (float*)w;  w += BT;
    char* Abuf = w;           w += SL;
    char* Bbuf = w;           w += QKVB;
    char* Fbuf = w;           w += F1B;
    bf16_t* x = (bf16_t*)Abuf;
    bf16_t* ctx = (bf16_t*)Abuf;
    bf16_t* hbuf = (bf16_t*)Abuf;
    bf16_t* qkv = (bf16_t*)Bbuf;
    bf16_t* part = (bf16_t*)Bbuf;
    bf16_t* y = (bf16_t*)(Bbuf + 2 * SL);
    bf16_t* vtg = (bf16_t*)Fbuf;
    bf16_t* f1 = (bf16_t*)Fbuf;

    bias_table_kernel<<<128, 256, 0, stream>>>(rel_bias, btab);
    rmsnorm_kernel<<<M, 256, 0, stream>>>(hs, ln1_w, x);

    gemm_bt<64, true, 0><<<dim3(32, 24, 1), 256, 0, stream>>>(
        x, wq, wk, wvv, qkv, M, D, D, 3072, 1024);
    transpose_v_kernel<<<gtv, 256, 0, stream>>>(qkv, vtg);
    attn_kernel<<<ga, 256, 0, stream>>>(qkv, vtg, btab, ctx);

    gemm_bt<64, true, 0><<<dim3(32, 8, 2), 256, 0, stream>>>(
        ctx, wo, wo, wo, part, M, D, D / 2, D, 1 << 30);
    reduce_rms_kernel<<<1024, 256, 0, stream>>>(part, 2, hs, ln2_w, hbuf, y);

    gemm_bt<64, true, 2><<<dim3(32, 32, 1), 256, 0, stream>>>(
        y, wi, wi, wi, f1, M, D, D, FF, 1 << 30);

    gemm_bt<64, true, 0><<<dim3(32, 8, 2), 256, 0, stream>>>(
        f1, wo_ff, wo_ff, wo_ff, part, M, FF, FF / 2, D, 1 << 30);
    reduce_out_kernel<<<1024, 256, 0, stream>>>(part, 2, hbuf, out);
  }
}

// Round 9
// 236.839 us; speedup vs baseline: 2.3402x; 1.0465x over previous
//
#include <hip/hip_runtime.h>
#include <hip/hip_bf16.h>
#include <math.h>

// T5 encoder block on MI355X (gfx950). B=2, S=1024, D_MODEL=1024, H=16,
// D_KV=64, D_FF=4096. Harness buffers fp32 (ws = 256 MiB -> full plan).
// Internal bf16 MFMA, fp32 acc.
// ROUND 9: GEMM K-loop rework — BK=64 (half the barriers), XOR-swizzled
// LDS (conflict-free ds_read_b128; source-side swizzle keeps DMA dest
// linear), XCD stripe swizzle for W-tile L2 reuse.

typedef __bf16 bf16_t;
typedef __attribute__((ext_vector_type(8))) __bf16 bf16x8;
typedef __attribute__((ext_vector_type(4))) __bf16 bf16x4;
typedef __attribute__((ext_vector_type(4))) float floatx4;

#define GLOBAL_AS(p) ((const __attribute__((address_space(1))) void*)(p))
#define LDS_AS(p)    ((__attribute__((address_space(3))) void*)(p))

// ---------------------------------------------------------------------------
// Weights fp32 -> bf16 (full-ws plan only). wqkv_b packs [wq;wk;wv].
// ---------------------------------------------------------------------------
__global__ __launch_bounds__(256) void convert_w_kernel(
    const float* __restrict__ wq, const float* __restrict__ wk,
    const float* __restrict__ wv, const float* __restrict__ wo,
    const float* __restrict__ wi, const float* __restrict__ woff,
    bf16_t* __restrict__ wqkv_b, bf16_t* __restrict__ wo_b,
    bf16_t* __restrict__ wi_b, bf16_t* __restrict__ woff_b) {
  size_t idx = ((size_t)blockIdx.x * 256 + threadIdx.x) * 8;
  const float* src;
  bf16_t* dst;
  size_t off;
  if (idx < 3145728) {
    size_t sec = idx >> 20;
    src = sec == 0 ? wq : (sec == 1 ? wk : wv);
    dst = wqkv_b + (sec << 20);
    off = idx & 1048575;
  } else if (idx < 4194304) {
    src = wo; dst = wo_b; off = idx - 3145728;
  } else if (idx < 8388608) {
    src = wi; dst = wi_b; off = idx - 4194304;
  } else {
    src = woff; dst = woff_b; off = idx - 8388608;
  }
  float4 a = *(const float4*)(src + off);
  float4 b = *(const float4*)(src + off + 4);
  bf16x8 o;
  o[0] = (bf16_t)a.x; o[1] = (bf16_t)a.y; o[2] = (bf16_t)a.z; o[3] = (bf16_t)a.w;
  o[4] = (bf16_t)b.x; o[5] = (bf16_t)b.y; o[6] = (bf16_t)b.z; o[7] = (bf16_t)b.w;
  *(bf16x8*)(dst + off) = o;
}

// ---------------------------------------------------------------------------
// Relative-position bias table: table[h][dpos] = rel_bias[bucket(k-q)][h]
// ---------------------------------------------------------------------------
__global__ void bias_table_kernel(const float* __restrict__ rel_bias,
                                  float* __restrict__ table) {
  int idx = blockIdx.x * 256 + threadIdx.x;
  int h = idx >> 11;
  int dpos = idx & 2047;
  int delta = dpos - 1023;
  if (delta > 1023) delta = 1023;
  int side = (delta > 0) ? 16 : 0;
  int rp = (delta < 0) ? -delta : delta;
  int bucket;
  if (rp < 8) {
    bucket = side + rp;
  } else {
    float t3 = (logf((float)rp * 0.125f) / 2.7725887f) * 8.0f;
    int v = 8 + (int)t3;
    if (v > 15) v = 15;
    bucket = side + v;
  }
  table[idx] = rel_bias[bucket * 16 + h];
}

// ---------------------------------------------------------------------------
// RMSNorm (fp32 input), one block per row (D=1024), output bf16.
// ---------------------------------------------------------------------------
__global__ __launch_bounds__(256) void rmsnorm_kernel(
    const float* __restrict__ X, const float* __restrict__ w,
    bf16_t* __restrict__ Y) {
  const int D = 1024;
  int row = blockIdx.x;
  int t = threadIdx.x;
  float4 v = ((const float4*)(X + (size_t)row * D))[t];
  float f[4] = {v.x, v.y, v.z, v.w};
  float s = 0.f;
#pragma unroll
  for (int j = 0; j < 4; ++j) s += f[j] * f[j];
#pragma unroll
  for (int off = 32; off > 0; off >>= 1) s += __shfl_down(s, off);
  __shared__ float red[4];
  int lane = t & 63, wave = t >> 6;
  if (lane == 0) red[wave] = s;
  __syncthreads();
  float tot = red[0] + red[1] + red[2] + red[3];
  float scale = rsqrtf(tot * (1.0f / D) + 1e-6f);
  float4 wv4 = ((const float4*)w)[t];
  bf16x4 o;
  o[0] = (bf16_t)(f[0] * scale * wv4.x);
  o[1] = (bf16_t)(f[1] * scale * wv4.y);
  o[2] = (bf16_t)(f[2] * scale * wv4.z);
  o[3] = (bf16_t)(f[3] * scale * wv4.w);
  *(bf16x4*)(Y + (size_t)row * D + t * 4) = o;
}

// ---------------------------------------------------------------------------
// GEMM: C[M,N] = epilogue(A[M,K] @ W[N,K]^T over K-slice blockIdx.z).
// TBM in {64,128}, BN=128, BK=64, 4 waves (2x2), wave tile (TBM/2)x64.
// LDS layout: [row][8 chunks of 16B], physical chunk p holds source k-chunk
// p^(row&7)  ->  fragment reads (c*4+lq)^(row&7) spread over all 32 banks.
// DMA dest stays linear (wave-uniform base + lane*16); the swizzle is
// applied on the SOURCE address (gather).
// WF32: W fp32 + 3-way select (compact QKV); else bf16 DMA staging.
// OP: 0 = store, 2 = relu-store.  Output bf16 at C + z*M*N.
// XCD stripe swizzle: requires gridDim.y % 8 == 0 (all our launches).
// ---------------------------------------------------------------------------
template <int TBM, bool WF32, int OP>
__global__ __launch_bounds__(256, 2) void gemm_bt(
    const bf16_t* __restrict__ A, const void* __restrict__ W0,
    const void* __restrict__ W1, const void* __restrict__ W2,
    bf16_t* __restrict__ C, int M, int K_total, int klen, int N,
    int wsel_cols) {
  constexpr int MFRAG = TBM / 32;
  __shared__ bf16_t As[TBM * 64];
  __shared__ bf16_t Bs[128 * 64];

  const int tid = threadIdx.x;
  const int lane = tid & 63;
  const int wv = tid >> 6;
  const int wm = wv & 1;
  const int wn = wv >> 1;
  const int lr = lane & 15;
  const int lq = lane >> 4;

  // XCD stripe swizzle (bijection on (bx,by); XCD = lid%8 heuristic)
  int bx = blockIdx.x, by = blockIdx.y;
  {
    int gx = gridDim.x, gy = gridDim.y;
    int lid = by * gx + bx;
    int xcd = lid & 7, slot = lid >> 3;
    int per = gy >> 3;
    by = xcd * per + slot % per;
    bx = slot / per;
  }

  const size_t row0 = (size_t)bx * TBM;
  const size_t col0 = (size_t)by * 128;
  const int k0 = blockIdx.z * klen;

  const void* Ws = W0;
  size_t wc0 = col0;
  if ((int)col0 >= wsel_cols) {
    if ((int)col0 < 2 * wsel_cols) { Ws = W1; wc0 = col0 - wsel_cols; }
    else { Ws = W2; wc0 = col0 - 2 * (size_t)wsel_cols; }
  }

  const bf16_t* Abase = A + row0 * K_total;
  bf16_t* Cs = C + (size_t)blockIdx.z * M * N;

  floatx4 acc[MFRAG][4] = {};

  for (int kt = k0; kt < k0 + klen; kt += 64) {
    // A: TBM rows x 64 cols = TBM*8 chunks of 16B
#pragma unroll
    for (int i = 0; i < TBM / 32; ++i) {
      int chunk = i * 256 + tid;
      int r = chunk >> 3;
      int kc = ((chunk & 7) ^ (r & 7)) << 3;  // source-side XOR swizzle
      __builtin_amdgcn_global_load_lds(
          GLOBAL_AS(Abase + (size_t)r * K_total + kt + kc),
          LDS_AS(As + (size_t)(i * 256 + wv * 64) * 8), 16, 0, 0);
    }
    if constexpr (WF32) {
      const float* Wbase = (const float*)Ws + wc0 * K_total;
#pragma unroll
      for (int i = 0; i < 4; ++i) {
        int chunk = i * 256 + tid;
        int r = chunk >> 3;
        int kc = ((chunk & 7) ^ (r & 7)) << 3;
        const float* p = Wbase + (size_t)r * K_total + kt + kc;
        float4 f0 = *(const float4*)p;
        float4 f1v = *(const float4*)(p + 4);
        bf16x8 o;
        o[0] = (bf16_t)f0.x; o[1] = (bf16_t)f0.y;
        o[2] = (bf16_t)f0.z; o[3] = (bf16_t)f0.w;
        o[4] = (bf16_t)f1v.x; o[5] = (bf16_t)f1v.y;
        o[6] = (bf16_t)f1v.z; o[7] = (bf16_t)f1v.w;
        *(bf16x8*)(Bs + chunk * 8) = o;
      }
    } else {
      const bf16_t* Wbase = (const bf16_t*)Ws + wc0 * K_total;
#pragma unroll
      for (int i = 0; i < 4; ++i) {
        int chunk = i * 256 + tid;
        int r = chunk >> 3;
        int kc = ((chunk & 7) ^ (r & 7)) << 3;
        __builtin_amdgcn_global_load_lds(
            GLOBAL_AS(Wbase + (size_t)r * K_total + kt + kc),
            LDS_AS(Bs + (size_t)(i * 256 + wv * 64) * 8), 16, 0, 0);
      }
    }
    __syncthreads();

#pragma unroll
    for (int c = 0; c < 2; ++c) {
      bf16x8 af[MFRAG], bfr[4];
#pragma unroll
      for (int mi = 0; mi < MFRAG; ++mi) {
        int rr = wm * (TBM / 2) + mi * 16 + lr;
        int c8p = (c * 4 + lq) ^ (rr & 7);
        af[mi] = *(const bf16x8*)(As + rr * 64 + c8p * 8);
      }
#pragma unroll
      for (int nj = 0; nj < 4; ++nj) {
        int rr = wn * 64 + nj * 16 + lr;
        int c8p = (c * 4 + lq) ^ (rr & 7);
        bfr[nj] = *(const bf16x8*)(Bs + rr * 64 + c8p * 8);
      }
#pragma unroll
      for (int mi = 0; mi < MFRAG; ++mi)
#pragma unroll
        for (int nj = 0; nj < 4; ++nj)
          acc[mi][nj] = __builtin_amdgcn_mfma_f32_16x16x32_bf16(
              af[mi], bfr[nj], acc[mi][nj], 0, 0, 0);
    }
    __syncthreads();
  }

#pragma unroll
  for (int mi = 0; mi < MFRAG; ++mi) {
#pragma unroll
    for (int nj = 0; nj < 4; ++nj) {
      size_t r = row0 + wm * (TBM / 2) + mi * 16 + lq * 4;
      size_t c = col0 + wn * 64 + nj * 16 + lr;
#pragma unroll
      for (int t = 0; t < 4; ++t) {
        float v = acc[mi][nj][t];
        if (OP == 2) v = v > 0.f ? v : 0.f;
        Cs[(r + t) * N + c] = (bf16_t)v;
      }
    }
  }
}

// ---------------------------------------------------------------------------
// V transpose: qkv V-section [b,s,h,d] -> Vt_g[(b*16+h)*64 + d][s].
// ---------------------------------------------------------------------------
__global__ __launch_bounds__(256) void transpose_v_kernel(
    const bf16_t* __restrict__ QKV, bf16_t* __restrict__ VT) {
  __shared__ bf16_t T[64 * 65];
  const int s0 = blockIdx.x * 64;
  const int h = blockIdx.y;
  const int b = blockIdx.z;
  const int tid = threadIdx.x;

  const bf16_t* Vh = QKV + ((size_t)b * 1024) * 3072 + 2048 + h * 64;
#pragma unroll
  for (int i = 0; i < 2; ++i) {
    int c = i * 256 + tid;
    int r = c >> 3;
    int d8 = (c & 7) * 8;
    bf16x8 v = *(const bf16x8*)(Vh + (size_t)(s0 + r) * 3072 + d8);
#pragma unroll
    for (int j = 0; j < 8; ++j) T[r * 65 + d8 + j] = v[j];
  }
  __syncthreads();

  bf16_t* Og = VT + ((size_t)b * 16 + h) * 64 * 1024;
#pragma unroll
  for (int i = 0; i < 2; ++i) {
    int c = i * 256 + tid;
    int d = c >> 3;
    int s8 = (c & 7) * 8;
    bf16x8 o;
#pragma unroll
    for (int j = 0; j < 8; ++j) o[j] = T[(s8 + j) * 65 + d];
    *(bf16x8*)(Og + (size_t)d * 1024 + s0 + s8) = o;
  }
}

// ---------------------------------------------------------------------------
// Flash attention, T5 style.  Fragment-major LDS (conflict-free), S^T MFMA,
// constant-shift softmax.
// ---------------------------------------------------------------------------
__device__ __forceinline__ void attn_stage(const bf16_t* Kh, const bf16_t* Vg,
                                           int k0, bf16_t* Ksb, bf16_t* Vtb,
                                           int tid, int wv) {
  const int l16 = tid & 15;
  const int lo8 = ((tid & 63) >> 4) * 8;
#pragma unroll
  for (int i = 0; i < 2; ++i) {
    int bi = wv * 2 + i;
    int g = bi >> 1, c = bi & 1;
    __builtin_amdgcn_global_load_lds(
        GLOBAL_AS(Kh + (size_t)(k0 + g * 16 + l16) * 3072 + c * 32 + lo8),
        LDS_AS(Ksb + bi * 512), 16, 0, 0);
    __builtin_amdgcn_global_load_lds(
        GLOBAL_AS(Vg + (size_t)(g * 16 + l16) * 1024 + k0 + c * 32 + lo8),
        LDS_AS(Vtb + bi * 512), 16, 0, 0);
  }
}

__global__ __launch_bounds__(256) void attn_kernel(
    const bf16_t* __restrict__ QKV, const bf16_t* __restrict__ VT,
    const float* __restrict__ bias_table, bf16_t* __restrict__ O) {
  const int qt = blockIdx.x;
  const int h = blockIdx.y;
  const int b = blockIdx.z;
  const int tid = threadIdx.x;
  const int lane = tid & 63;
  const int wv = tid >> 6;
  const int lr = lane & 15;
  const int lq = lane >> 4;

  __shared__ bf16_t Ks[2][4096];
  __shared__ bf16_t Vt[2][4096];
  __shared__ bf16_t Ps[4][1024];

  const bf16_t* Qh = QKV + (size_t)b * 1024 * 3072 + h * 64;
  const bf16_t* Kh = Qh + 1024;
  const bf16_t* Vg = VT + ((size_t)b * 16 + h) * 64 * 1024;
  bf16_t* Oh = O + (size_t)b * 1024 * 1024 + h * 64;

  const int q0w = qt * 64 + wv * 16;
  const int myq = q0w + lr;

  bf16x8 qf[2];
#pragma unroll
  for (int c = 0; c < 2; ++c)
    qf[c] = *(const bf16x8*)(Qh + (size_t)(q0w + lr) * 3072 + c * 32 + lq * 8);

  float l_loc = 0.f;
  floatx4 o_acc[4];
#pragma unroll
  for (int i = 0; i < 4; ++i) o_acc[i] = (floatx4){0.f, 0.f, 0.f, 0.f};

  const float* btab = bias_table + h * 2048 + 1023 - myq;

  attn_stage(Kh, Vg, 0, Ks[0], Vt[0], tid, wv);
  __syncthreads();

  for (int kt = 0; kt < 16; ++kt) {
    const int k0 = kt * 64;
    if (kt < 15)
      attn_stage(Kh, Vg, k0 + 64, Ks[(kt + 1) & 1], Vt[(kt + 1) & 1], tid, wv);
    const bf16_t* Ksb = Ks[kt & 1];
    const bf16_t* Vtb = Vt[kt & 1];

    floatx4 s_acc[4];
#pragma unroll
    for (int g = 0; g < 4; ++g) {
      floatx4 a = (floatx4){0.f, 0.f, 0.f, 0.f};
#pragma unroll
      for (int c = 0; c < 2; ++c) {
        bf16x8 kf = *(const bf16x8*)(Ksb + (g * 2 + c) * 512 + lane * 8);
        a = __builtin_amdgcn_mfma_f32_16x16x32_bf16(kf, qf[c], a, 0, 0, 0);
      }
      s_acc[g] = a;
    }

#pragma unroll
    for (int g = 0; g < 4; ++g) {
      bf16x4 pb;
#pragma unroll
      for (int t = 0; t < 4; ++t) {
        int key = k0 + g * 16 + lq * 4 + t;
        float p = __expf(s_acc[g][t] + btab[key] - 32.0f);
        l_loc += p;
        pb[t] = (bf16_t)p;
      }
      int c = g >> 1;
      int dst = c * 512 + (((g & 1) * 2 + (lq >> 1)) * 16 + lr) * 8 + (lq & 1) * 4;
      *(bf16x4*)(&Ps[wv][dst]) = pb;
    }

    asm volatile("s_waitcnt lgkmcnt(0)" ::: "memory");

    bf16x8 pf[2];
#pragma unroll
    for (int c = 0; c < 2; ++c)
      pf[c] = *(const bf16x8*)(&Ps[wv][c * 512 + lane * 8]);

#pragma unroll
    for (int g = 0; g < 4; ++g) {
#pragma unroll
      for (int c = 0; c < 2; ++c) {
        bf16x8 vf = *(const bf16x8*)(Vtb + (g * 2 + c) * 512 + lane * 8);
        o_acc[g] = __builtin_amdgcn_mfma_f32_16x16x32_bf16(pf[c], vf, o_acc[g], 0, 0, 0);
      }
    }
    __syncthreads();
  }

  l_loc += __shfl_xor(l_loc, 16);
  l_loc += __shfl_xor(l_loc, 32);
  float inv = 1.f / l_loc;

  float invt[4];
#pragma unroll
  for (int t = 0; t < 4; ++t) invt[t] = __shfl(inv, lq * 4 + t);

#pragma unroll
  for (int g = 0; g < 4; ++g) {
#pragma unroll
    for (int t = 0; t < 4; ++t) {
      int qg = q0w + lq * 4 + t;
      int d = g * 16 + lr;
      Oh[(size_t)qg * 1024 + d] = (bf16_t)(o_acc[g][t] * invt[t]);
    }
  }
}

// ---------------------------------------------------------------------------
// Split-K reduce + fp32 residual + fused RMSNorm.
// ---------------------------------------------------------------------------
__global__ __launch_bounds__(256) void reduce_rms_kernel(
    const bf16_t* __restrict__ part, int splits, const float* __restrict__ hs,
    const float* __restrict__ ln2w, bf16_t* __restrict__ hbuf,
    bf16_t* __restrict__ y) {
  const size_t SLICE = (size_t)2048 * 1024;
  int tid = threadIdx.x;
  size_t i = ((size_t)blockIdx.x * 256 + tid) * 8;

  float s[8] = {};
  for (int sp = 0; sp < splits; ++sp) {
    bf16x8 p = *(const bf16x8*)(part + sp * SLICE + i);
#pragma unroll
    for (int j = 0; j < 8; ++j) s[j] += (float)p[j];
  }
  float4 a = *(const float4*)(hs + i);
  float4 b = *(const float4*)(hs + i + 4);
  s[0] += a.x; s[1] += a.y; s[2] += a.z; s[3] += a.w;
  s[4] += b.x; s[5] += b.y; s[6] += b.z; s[7] += b.w;

  bf16x8 hb;
#pragma unroll
  for (int j = 0; j < 8; ++j) hb[j] = (bf16_t)s[j];
  *(bf16x8*)(hbuf + i) = hb;

  float ss = 0.f;
#pragma unroll
  for (int j = 0; j < 8; ++j) ss += s[j] * s[j];
#pragma unroll
  for (int off = 32; off > 0; off >>= 1) ss += __shfl_down(ss, off);
  __shared__ float red[4];
  int wave = tid >> 6;
  if ((tid & 63) == 0) red[wave] = ss;
  __syncthreads();
  float rowss = (tid < 128) ? (red[0] + red[1]) : (red[2] + red[3]);
  float scale = rsqrtf(rowss * (1.f / 1024.f) + 1e-6f);

  int col = (int)(i & 1023);
  float4 w0 = *(const float4*)(ln2w + col);
  float4 w1 = *(const float4*)(ln2w + col + 4);
  bf16x8 o;
  o[0] = (bf16_t)(s[0] * scale * w0.x); o[1] = (bf16_t)(s[1] * scale * w0.y);
  o[2] = (bf16_t)(s[2] * scale * w0.z); o[3] = (bf16_t)(s[3] * scale * w0.w);
  o[4] = (bf16_t)(s[4] * scale * w1.x); o[5] = (bf16_t)(s[5] * scale * w1.y);
  o[6] = (bf16_t)(s[6] * scale * w1.z); o[7] = (bf16_t)(s[7] * scale * w1.w);
  *(bf16x8*)(y + i) = o;
}

// ---------------------------------------------------------------------------
// Final split-K reduce + bf16 residual -> fp32 output.
// ---------------------------------------------------------------------------
__global__ __launch_bounds__(256) void reduce_out_kernel(
    const bf16_t* __restrict__ part, int splits,
    const bf16_t* __restrict__ res, float* __restrict__ out) {
  const size_t SLICE = (size_t)2048 * 1024;
  size_t i = ((size_t)blockIdx.x * 256 + threadIdx.x) * 8;
  float s[8] = {};
  for (int sp = 0; sp < splits; ++sp) {
    bf16x8 p = *(const bf16x8*)(part + sp * SLICE + i);
#pragma unroll
    for (int j = 0; j < 8; ++j) s[j] += (float)p[j];
  }
  bf16x8 r = *(const bf16x8*)(res + i);
#pragma unroll
  for (int j = 0; j < 8; ++j) s[j] += (float)r[j];
  float4 a, b;
  a.x = s[0]; a.y = s[1]; a.z = s[2]; a.w = s[3];
  b.x = s[4]; b.y = s[5]; b.z = s[6]; b.w = s[7];
  *(float4*)(out + i) = a;
  *(float4*)(out + i + 4) = b;
}

// ---------------------------------------------------------------------------
extern "C" void kernel_launch(void* const* d_in, const int* in_sizes, int n_in,
                              void* d_out, int out_size, void* d_ws,
                              size_t ws_size, hipStream_t stream) {
  const float* hs = (const float*)d_in[0];
  const float* ln1_w = (const float*)d_in[1];
  const float* wq = (const float*)d_in[2];
  const float* wk = (const float*)d_in[3];
  const float* wvv = (const float*)d_in[4];
  const float* wo = (const float*)d_in[5];
  const float* rel_bias = (const float*)d_in[6];
  const float* ln2_w = (const float*)d_in[7];
  const float* wi = (const float*)d_in[8];
  const float* wo_ff = (const float*)d_in[9];
  float* out = (float*)d_out;

  const int M = 2048, D = 1024, FF = 4096;
  const size_t SL = (size_t)M * D * 2;
  const size_t QKVB = (size_t)M * 3072 * 2;
  const size_t F1B = (size_t)M * FF * 2;
  const size_t BT = 16 * 2048 * 4;

  const size_t FULL_NEED = BT + 6291456 + 2097152 + 8388608 + 8388608 +
                           SL + QKVB + SL + SL + SL + F1B + SL + 4 * SL;
  const size_t COMPACT_NEED = BT + SL + QKVB + F1B;  // 33,685,504 (proven)

  char* w = (char*)d_ws;
  dim3 gtv(16, 16, 2), ga(16, 16, 2);

  if (ws_size >= FULL_NEED) {
    float* btab = (float*)w;      w += BT;
    bf16_t* wqkv_b = (bf16_t*)w;  w += 6291456;
    bf16_t* wo_b = (bf16_t*)w;    w += 2097152;
    bf16_t* wi_b = (bf16_t*)w;    w += 8388608;
    bf16_t* woff_b = (bf16_t*)w;  w += 8388608;
    bf16_t* x = (bf16_t*)w;       w += SL;
    bf16_t* qkv = (bf16_t*)w;     w += QKVB;
    bf16_t* ctx = (bf16_t*)w;     w += SL;
    bf16_t* hbuf = (bf16_t*)w;    w += SL;
    bf16_t* y = (bf16_t*)w;       w += SL;
    bf16_t* f1 = (bf16_t*)w;      w += F1B;
    bf16_t* vtg = (bf16_t*)w;     w += SL;
    bf16_t* part = (bf16_t*)w;    w += 4 * SL;

    convert_w_kernel<<<6144, 256, 0, stream>>>(wq, wk, wvv, wo, wi, wo_ff,
                                               wqkv_b, wo_b, wi_b, woff_b);
    bias_table_kernel<<<128, 256, 0, stream>>>(rel_bias, btab);
    rmsnorm_kernel<<<M, 256, 0, stream>>>(hs, ln1_w, x);

    // QKV: 128-tile, (16,24) = 384 blocks, BK=64 -> 16 iters
    gemm_bt<128, false, 0><<<dim3(16, 24, 1), 256, 0, stream>>>(
        x, wqkv_b, wqkv_b, wqkv_b, qkv, M, D, D, 3072, 1 << 30);
    transpose_v_kernel<<<gtv, 256, 0, stream>>>(qkv, vtg);
    attn_kernel<<<ga, 256, 0, stream>>>(qkv, vtg, btab, ctx);

    // WO: 128-tile split-K=4 -> (16,8,4) = 512 blocks, K=256 -> 4 iters
    gemm_bt<128, false, 0><<<dim3(16, 8, 4), 256, 0, stream>>>(
        ctx, wo_b, wo_b, wo_b, part, M, D, D / 4, D, 1 << 30);
    reduce_rms_kernel<<<1024, 256, 0, stream>>>(part, 4, hs, ln2_w, hbuf, y);

    // WI: 128-tile, (16,32) = 512 blocks, 16 iters
    gemm_bt<128, false, 2><<<dim3(16, 32, 1), 256, 0, stream>>>(
        y, wi_b, wi_b, wi_b, f1, M, D, D, FF, 1 << 30);

    // WO_FF: 128-tile split-K=4 -> 512 blocks, K=1024 -> 16 iters
    gemm_bt<128, false, 0><<<dim3(16, 8, 4), 256, 0, stream>>>(
        f1, woff_b, woff_b, woff_b, part, M, FF, FF / 4, D, 1 << 30);
    reduce_out_kernel<<<1024, 256, 0, stream>>>(part, 4, hbuf, out);
  } else {
    if (ws_size < COMPACT_NEED) return;
    float* btab = (float*)w;  w += BT;
    char* Abuf = w;           w += SL;
    char* Bbuf = w;           w += QKVB;
    char* Fbuf = w;           w += F1B;
    bf16_t* x = (bf16_t*)Abuf;
    bf16_t* ctx = (bf16_t*)Abuf;
    bf16_t* hbuf = (bf16_t*)Abuf;
    bf16_t* qkv = (bf16_t*)Bbuf;
    bf16_t* part = (bf16_t*)Bbuf;
    bf16_t* y = (bf16_t*)(Bbuf + 2 * SL);
    bf16_t* vtg = (bf16_t*)Fbuf;
    bf16_t* f1 = (bf16_t*)Fbuf;

    bias_table_kernel<<<128, 256, 0, stream>>>(rel_bias, btab);
    rmsnorm_kernel<<<M, 256, 0, stream>>>(hs, ln1_w, x);

    gemm_bt<64, true, 0><<<dim3(32, 24, 1), 256, 0, stream>>>(
        x, wq, wk, wvv, qkv, M, D, D, 3072, 1024);
    transpose_v_kernel<<<gtv, 256, 0, stream>>>(qkv, vtg);
    attn_kernel<<<ga, 256, 0, stream>>>(qkv, vtg, btab, ctx);

    gemm_bt<64, true, 0><<<dim3(32, 8, 2), 256, 0, stream>>>(
        ctx, wo, wo, wo, part, M, D, D / 2, D, 1 << 30);
    reduce_rms_kernel<<<1024, 256, 0, stream>>>(part, 2, hs, ln2_w, hbuf, y);

    gemm_bt<64, true, 2><<<dim3(32, 32, 1), 256, 0, stream>>>(
        y, wi, wi, wi, f1, M, D, D, FF, 1 << 30);

    gemm_bt<64, true, 0><<<dim3(32, 8, 2), 256, 0, stream>>>(
        f1, wo_ff, wo_ff, wo_ff, part, M, FF, FF / 2, D, 1 << 30);
    reduce_out_kernel<<<1024, 256, 0, stream>>>(part, 2, hbuf, out);
  }
}